// Round 10
// baseline (920.840 us; speedup 1.0000x reference)
//
#include <hip/hip_runtime.h>
#include <hip/hip_bf16.h>

#define H 128
#define EFD 8
#define NLAYER 4
#define ZDIM (2*H+EFD)   // 264

typedef float f32x2 __attribute__((ext_vector_type(2)));
typedef float f32x4 __attribute__((ext_vector_type(4)));
typedef short s16x8 __attribute__((ext_vector_type(8)));
typedef _Float16 f16x4 __attribute__((ext_vector_type(4)));

// packed fp32 fma with src0 broadcast from low/high half (VOP3P op_sel)
#define PKFMA_LO(acc, a, b) asm("v_pk_fma_f32 %0, %1, %2, %0 op_sel:[0,0,0] op_sel_hi:[0,1,1]" : "+v"(acc) : "v"(a), "v"(b))
#define PKFMA_HI(acc, a, b) asm("v_pk_fma_f32 %0, %1, %2, %0 op_sel:[1,0,0] op_sel_hi:[1,1,1]" : "+v"(acc) : "v"(a), "v"(b))
#define PKFMA_LO_INIT(dst, a, b, c) asm("v_pk_fma_f32 %0, %1, %2, %3 op_sel:[0,0,0] op_sel_hi:[0,1,1]" : "=v"(dst) : "v"(a), "v"(b), "v"(c))

#define L2E 1.44269504088896340736f
#define LN2 0.69314718055994530942f
#define OPITCH 520   // fp16 pitch for LDS out-tile: 1040B rows (16B-aligned)

__device__ __forceinline__ unsigned short f2bf(float x){
    unsigned u = __float_as_uint(x);
    return (unsigned short)((u + 0x7FFFu + ((u>>16)&1u)) >> 16);
}

// h = relu(x @ W_emb + b_emb)   [N,16]@[16,128]
__global__ void embed_kernel(const float* __restrict__ x, const float* __restrict__ We,
                             const float* __restrict__ be, float* __restrict__ h, int N){
    int idx = blockIdx.x*blockDim.x + threadIdx.x;
    if (idx >= N*H) return;
    int n = idx >> 7, f = idx & 127;
    float a = be[f];
    #pragma unroll
    for (int k=0;k<16;k++) a = fmaf(x[n*16+k], We[k*H+f], a);
    h[idx] = fmaxf(a, 0.f);
}

__global__ void hist_kernel(const int* __restrict__ dstI, int* __restrict__ counts, int E){
    int e = blockIdx.x*blockDim.x + threadIdx.x;
    if (e < E) atomicAdd(&counts[dstI[e]], 1);
}

__global__ __launch_bounds__(1024) void scan1(const int* __restrict__ counts, int* __restrict__ incl,
                                              int* __restrict__ bsums, int N){
    __shared__ int lds[1024];
    int t = threadIdx.x;
    int i = blockIdx.x*1024 + t;
    int v = (i < N) ? counts[i] : 0;
    lds[t] = v;
    __syncthreads();
    for (int off=1; off<1024; off<<=1){
        int add = (t>=off) ? lds[t-off] : 0;
        __syncthreads();
        lds[t] += add;
        __syncthreads();
    }
    if (i < N) incl[i] = lds[t];
    if (t == 1023) bsums[blockIdx.x] = lds[1023];
}

__global__ void scan2(int* bsums, int nb){
    if (threadIdx.x == 0){
        int run = 0;
        for (int b=0;b<nb;b++){ int v = bsums[b]; bsums[b] = run; run += v; }
    }
}

__global__ __launch_bounds__(1024) void scan3(const int* incl, const int* __restrict__ counts,
                                              const int* __restrict__ bsums, int* __restrict__ rowptr,
                                              int* cursor, int N, int E){
    int i = blockIdx.x*1024 + threadIdx.x;
    if (i >= N) return;
    int ex = incl[i] - counts[i] + bsums[blockIdx.x];
    rowptr[i] = ex;
    cursor[i] = ex;
    if (i == N-1) rowptr[N] = E;
}

__global__ void scatter_kernel(const int* __restrict__ srcI, const int* __restrict__ dstI,
                               const float* __restrict__ eattr, int* __restrict__ cursor,
                               int* __restrict__ src_s, float* __restrict__ ea_s, int E){
    int e = blockIdx.x*blockDim.x + threadIdx.x;
    if (e >= E) return;
    int d = dstI[e];
    int pos = atomicAdd(&cursor[d], 1);
    src_s[pos] = srcI[e];
    const float4* s4 = (const float4*)(eattr + (size_t)e*EFD);
    float4* o4 = (float4*)(ea_s + (size_t)pos*EFD);
    o4[0] = s4[0]; o4[1] = s4[1];
}

// Pack node-part weights (rows 0..255 of Wf/Ws, all 4 layers) into per-lane MFMA B
// fragments, split hi/lo bf16. Index: idx = ((layer*4 + w)*4 + ks)*8*64 + ct*64 + lane.
__global__ __launch_bounds__(256) void wpack_kernel(const float* __restrict__ Wf, const float* __restrict__ Ws,
        s16x8* __restrict__ bhi, s16x8* __restrict__ blo){
    int idx = blockIdx.x*256 + threadIdx.x;   // 32768 total
    int l = idx & 63, ct = (idx>>6)&7, ks = (idx>>9)&3, w = (idx>>11)&3, layer = idx>>13;
    int cp = w*128 + ct*16 + (l&15);
    int k0 = ks*32 + ((l>>4)<<3);
    const float* WfL = Wf + (size_t)layer*ZDIM*H;
    const float* WsL = Ws + (size_t)layer*ZDIM*H;
    int colIn = cp & 127;
    int sel = cp >> 7;
    const float* Wm = (sel & 1) ? WsL : WfL;
    int krow = (sel >> 1) ? H : 0;
    s16x8 vh, vl;
    #pragma unroll
    for (int e=0;e<8;e++){
        float v = Wm[(size_t)(krow + k0 + e)*H + colIn];
        unsigned short hb = f2bf(v);
        float rem = v - __uint_as_float(((unsigned)hb)<<16);
        vh[e] = (short)hb;
        vl[e] = (short)f2bf(rem);
    }
    bhi[idx] = vh;
    blo[idx] = vl;
}

// Persistent pipelined [N,128]@[128,512] GEMM, bf16 MFMA 3-term hi/lo split.
// 512 blocks x 512 threads (8 waves, 2 blocks/CU), register-resident B fragments.
// Epilogue via LDS transpose -> coalesced 16B stores. Output fp16 table T16[N][512]:
// 0..255 dst {Fd2k,Fd2k+1,Sd2k,Sd2k+1} (bias baked), 256..511 src. Pre-scaled by
// log2(e). Fused BN-apply (layers>0): h += relu(xn*sc+sh) in-place.
__global__ __launch_bounds__(512, 2) void table_mfma(
        float* __restrict__ h, const float* __restrict__ xn, const float* __restrict__ scsh,
        const s16x8* __restrict__ bhi, const s16x8* __restrict__ blo,
        const float* __restrict__ bf_l, const float* __restrict__ bs_l,
        _Float16* __restrict__ T16, int N, int layer, int ntiles){
    __shared__ __align__(16) short amat[2][32*136];        // hi/lo, 272B row pitch
    __shared__ __align__(16) _Float16 outs[32*OPITCH];     // 32 rows x 520 fp16
    const int t = threadIdx.x;
    const int lane = t & 63, W = t >> 6;
    const int ow = W >> 1, ctbase = (W & 1)*4;
    const int rbase = lane & 15, kg = lane >> 4;

    // ---- B fragments: load once, pin in VGPRs ----
    s16x8 Bh[4][4], Bl[4][4];
    {
        const size_t bbase = ((size_t)layer*4 + ow)*2048;
        #pragma unroll
        for (int ks=0;ks<4;ks++)
            #pragma unroll
            for (int c=0;c<4;c++){
                Bh[ks][c] = bhi[bbase + ks*512 + (ctbase+c)*64 + lane];
                Bl[ks][c] = blo[bbase + ks*512 + (ctbase+c)*64 + lane];
            }
        #pragma unroll
        for (int ks=0;ks<4;ks++)
            #pragma unroll
            for (int c=0;c<4;c++) asm volatile("" : "+v"(Bh[ks][c]), "+v"(Bl[ks][c]));
    }
    // ---- per-lane output constants ----
    int offT[4];
    float bv[4];
    #pragma unroll
    for (int c=0;c<4;c++){
        const int cl = (ctbase+c)*16 + rbase;
        offT[c] = (ow>>1)*256 + ((cl>>1)<<2) + ((ow&1)<<1) + (cl&1);
        bv[c] = (ow == 0) ? bf_l[cl]*L2E : (ow == 1) ? bs_l[cl]*L2E : 0.f;
    }
    // ---- staging constants ----
    const int srow = t >> 4;          // 0..31
    const int kb = (t & 15)*8;        // 0..120
    float sc8[8], sh8[8];
    if (scsh){
        #pragma unroll
        for (int q=0;q<8;q+=4){
            *(float4*)&sc8[q] = *(const float4*)(scsh + kb + q);
            *(float4*)&sh8[q] = *(const float4*)(scsh + H + kb + q);
        }
    }

    const int stride = gridDim.x;
    int tile = blockIdx.x;
    float4 ph0, ph1, px0, px1;
    auto PREF = [&](int tl){
        const int gn = tl*32 + srow;
        const bool v = (gn < N);
        const float* hr = h + (size_t)gn*H + kb;
        ph0 = v ? *(const float4*)(hr)     : make_float4(0.f,0.f,0.f,0.f);
        ph1 = v ? *(const float4*)(hr + 4) : make_float4(0.f,0.f,0.f,0.f);
        if (scsh){
            const float* xr = xn + (size_t)gn*H + kb;
            px0 = v ? *(const float4*)(xr)     : make_float4(0.f,0.f,0.f,0.f);
            px1 = v ? *(const float4*)(xr + 4) : make_float4(0.f,0.f,0.f,0.f);
        }
    };
    PREF(tile);
    for (; tile < ntiles; tile += stride){
        const int n0 = tile*32;
        {   // ---- cvt + (fused BN) + LDS write, from prefetched regs ----
            const int gn = n0 + srow;
            const bool valid = gn < N;
            float vv[8];
            if (scsh){
                #pragma unroll
                for (int q=0;q<4;q++){
                    vv[q]   = (&ph0.x)[q] + fmaxf(fmaf((&px0.x)[q], sc8[q],   sh8[q]),   0.f);
                    vv[q+4] = (&ph1.x)[q] + fmaxf(fmaf((&px1.x)[q], sc8[q+4], sh8[q+4]), 0.f);
                }
                if (valid){
                    float* hr = h + (size_t)gn*H + kb;
                    float4 o0; o0.x=vv[0]; o0.y=vv[1]; o0.z=vv[2]; o0.w=vv[3];
                    float4 o1; o1.x=vv[4]; o1.y=vv[5]; o1.z=vv[6]; o1.w=vv[7];
                    *(float4*)(hr)     = o0;
                    *(float4*)(hr + 4) = o1;
                }
            } else {
                #pragma unroll
                for (int q=0;q<4;q++){ vv[q] = (&ph0.x)[q]; vv[q+4] = (&ph1.x)[q]; }
            }
            s16x8 hv2, lv2;
            #pragma unroll
            for (int q=0;q<8;q++){
                unsigned short hb = f2bf(vv[q]);
                float rem = vv[q] - __uint_as_float(((unsigned)hb)<<16);
                hv2[q] = (short)hb;
                lv2[q] = (short)f2bf(rem);
            }
            *(s16x8*)&amat[0][srow*136 + kb] = hv2;
            *(s16x8*)&amat[1][srow*136 + kb] = lv2;
        }
        __syncthreads();
        PREF(tile + stride);   // issue next tile's loads; latency hides under MFMA+stores
        // ---- MFMA ----
        f32x4 acc[2][4];
        #pragma unroll
        for (int rt=0;rt<2;rt++)
            #pragma unroll
            for (int c=0;c<4;c++){ acc[rt][c][0]=0.f; acc[rt][c][1]=0.f; acc[rt][c][2]=0.f; acc[rt][c][3]=0.f; }
        #pragma unroll
        for (int ks=0;ks<4;ks++){
            s16x8 ah[2], al[2];
            #pragma unroll
            for (int rt=0;rt<2;rt++){
                const int ao = (rbase + 16*rt)*136 + ks*32 + kg*8;
                ah[rt] = *(const s16x8*)&amat[0][ao];
                al[rt] = *(const s16x8*)&amat[1][ao];
            }
            #pragma unroll
            for (int c=0;c<4;c++)
                #pragma unroll
                for (int rt=0;rt<2;rt++){
                    acc[rt][c] = __builtin_amdgcn_mfma_f32_16x16x32_bf16(ah[rt], Bh[ks][c], acc[rt][c], 0, 0, 0);
                    acc[rt][c] = __builtin_amdgcn_mfma_f32_16x16x32_bf16(ah[rt], Bl[ks][c], acc[rt][c], 0, 0, 0);
                    acc[rt][c] = __builtin_amdgcn_mfma_f32_16x16x32_bf16(al[rt], Bh[ks][c], acc[rt][c], 0, 0, 0);
                }
        }
        // ---- C fragments -> LDS out-tile (fp16) ----
        #pragma unroll
        for (int c=0;c<4;c++)
            #pragma unroll
            for (int rt=0;rt<2;rt++){
                const int nrow = 16*rt + kg*4;
                #pragma unroll
                for (int r=0;r<4;r++)
                    outs[(nrow + r)*OPITCH + offT[c]] = (_Float16)fmaf(acc[rt][c][r], L2E, bv[c]);
            }
        __syncthreads();
        // ---- coalesced copy-out: wave W handles rows W, W+8, W+16, W+24; 1KB/row ----
        {
            const int colb = (t & 63)*8;   // fp16 offset, 16B per lane
            #pragma unroll
            for (int ps=0; ps<4; ps++){
                const int row = ps*8 + W;
                const int nd = n0 + row;
                if (nd < N){
                    uint4 v = *(const uint4*)&outs[row*OPITCH + colb];
                    *(uint4*)(T16 + (size_t)nd*512 + colb) = v;
                }
            }
        }
        __syncthreads();
    }
}

// One wave per node. Edge-weight block loaded from GLOBAL straight into registers
// (no LDS copy exists -> compiler cannot rematerialize it inside the edge loop).
// Packed fp32 fma; exp2-domain gates; 3-deep gather prefetch; uniform s_load ids.
__global__ __launch_bounds__(256, 4) void agg_kernel(
        const _Float16* __restrict__ T16,
        const int* __restrict__ rowptr, const int* __restrict__ src_s, const float* __restrict__ ea_s,
        const float* __restrict__ Wf_l, const float* __restrict__ Ws_l,
        const float* __restrict__ h, float* __restrict__ xn, int N){
    const int t = threadIdx.x;
    const int k = t & 63;
    const int i = blockIdx.x*4 + (t >> 6);
    if (i >= N) return;
    // weights: per-lane 2 columns of the 8x128 edge blocks; wave-row = one 512B line
    f32x2 wef2[8], wes2[8];
    {
        const float* wf = Wf_l + 2*H*H + 2*k;
        const float* ws = Ws_l + 2*H*H + 2*k;
        #pragma unroll
        for (int r=0;r<8;r++){
            f32x2 a = *(const f32x2*)(wf + r*H);
            f32x2 b = *(const f32x2*)(ws + r*H);
            wef2[r].x = a.x*L2E; wef2[r].y = a.y*L2E;
            wes2[r].x = b.x*L2E; wes2[r].y = b.y*L2E;
        }
        #pragma unroll
        for (int r=0;r<8;r++) asm volatile("" : "+v"(wef2[r]), "+v"(wes2[r]));
    }
    // dst gate bases (bias already baked in table)
    f16x4 dv = *(const f16x4*)(T16 + ((size_t)i << 9) + 4*k);
    f32x2 fd2, sd2;
    fd2.x = (float)dv[0]; fd2.y = (float)dv[1];
    sd2.x = (float)dv[2]; sd2.y = (float)dv[3];
    f32x2 acc = {0.f, 0.f};
    const int e0 = __builtin_amdgcn_readfirstlane(rowptr[i]);
    const int e1 = __builtin_amdgcn_readfirstlane(rowptr[i+1]);
    const _Float16* Ts = T16 + 256 + 4*k;   // src half, per-lane offset
    const int j0 = (e0   < e1) ? src_s[e0]   : 0;   // uniform -> s_load
    const int j1 = (e0+1 < e1) ? src_s[e0+1] : j0;
    const int j2 = (e0+2 < e1) ? src_s[e0+2] : j1;
    f16x4 tvA = *(const f16x4*)(Ts + ((size_t)(unsigned)j0 << 9));
    f16x4 tvB = *(const f16x4*)(Ts + ((size_t)(unsigned)j1 << 9));
    f16x4 tvC = *(const f16x4*)(Ts + ((size_t)(unsigned)j2 << 9));
    for (int e = e0; e < e1; ++e){
        const int ec = (e+3 < e1) ? (e+3) : (e1-1);
        const int jn = src_s[ec];                    // uniform -> s_load
        f16x4 tvD = *(const f16x4*)(Ts + ((size_t)(unsigned)jn << 9));
        const float* ep = ea_s + (size_t)e*EFD;
        f32x4 eaA = *(const f32x4*)(ep);
        f32x4 eaB = *(const f32x4*)(ep + 4);
        f32x2 ea0 = __builtin_shufflevector(eaA, eaA, 0, 1);
        f32x2 ea1 = __builtin_shufflevector(eaA, eaA, 2, 3);
        f32x2 ea2 = __builtin_shufflevector(eaB, eaB, 0, 1);
        f32x2 ea3 = __builtin_shufflevector(eaB, eaB, 2, 3);
        f32x2 ef, es;
        PKFMA_LO_INIT(ef, ea0, wef2[0], fd2);
        PKFMA_HI(ef, ea0, wef2[1]);
        PKFMA_LO(ef, ea1, wef2[2]); PKFMA_HI(ef, ea1, wef2[3]);
        PKFMA_LO(ef, ea2, wef2[4]); PKFMA_HI(ef, ea2, wef2[5]);
        PKFMA_LO(ef, ea3, wef2[6]); PKFMA_HI(ef, ea3, wef2[7]);
        PKFMA_LO_INIT(es, ea0, wes2[0], sd2);
        PKFMA_HI(es, ea0, wes2[1]);
        PKFMA_LO(es, ea1, wes2[2]); PKFMA_HI(es, ea1, wes2[3]);
        PKFMA_LO(es, ea2, wes2[4]); PKFMA_HI(es, ea2, wes2[5]);
        PKFMA_LO(es, ea3, wes2[6]); PKFMA_HI(es, ea3, wes2[7]);
        f32x2 g = ef, p = es;
        g.x += (float)tvA[0]; g.y += (float)tvA[1];
        p.x += (float)tvA[2]; p.y += (float)tvA[3];
        float sx = __builtin_amdgcn_rcpf(1.0f + __builtin_amdgcn_exp2f(-g.x));
        float sy = __builtin_amdgcn_rcpf(1.0f + __builtin_amdgcn_exp2f(-g.y));
        float tx = fmaxf(p.x, 0.f) + __builtin_amdgcn_logf(1.0f + __builtin_amdgcn_exp2f(-fabsf(p.x)));
        float ty = fmaxf(p.y, 0.f) + __builtin_amdgcn_logf(1.0f + __builtin_amdgcn_exp2f(-fabsf(p.y)));
        acc.x = fmaf(sx*tx, LN2, acc.x);
        acc.y = fmaf(sy*ty, LN2, acc.y);
        tvA = tvB; tvB = tvC; tvC = tvD;
    }
    f32x2 hv = *(const f32x2*)(h + ((size_t)i << 7) + 2*k);
    f32x2 o = acc + hv;
    *(f32x2*)(xn + ((size_t)i << 7) + 2*k) = o;
}

__global__ __launch_bounds__(256) void stats_kernel(const float* __restrict__ xn, double* __restrict__ sums, int N){
    __shared__ double l1[128], l2[128];
    const int f = threadIdx.x & 127;
    const int half = threadIdx.x >> 7;
    const int nb = gridDim.x;
    const int per = (N + nb - 1)/nb;
    const int r0 = blockIdx.x*per;
    const int r1 = min(N, r0+per);
    double s = 0.0, s2 = 0.0;
    for (int r=r0+half; r<r1; r+=2){
        float v = xn[(size_t)r*H + f];
        s += v; s2 += (double)v*(double)v;
    }
    if (half == 1){ l1[f] = s; l2[f] = s2; }
    __syncthreads();
    if (half == 0){
        s += l1[f]; s2 += l2[f];
        atomicAdd(&sums[f], s);
        atomicAdd(&sums[H+f], s2);
    }
}

__global__ void finalize_bn(double* __restrict__ sums, const float* __restrict__ gamma_l,
                            const float* __restrict__ beta_l, float* __restrict__ scsh, int N){
    int f = threadIdx.x;
    if (f >= H) return;
    double mu = sums[f]/(double)N;
    double var = sums[H+f]/(double)N - mu*mu;
    if (var < 0.0) var = 0.0;
    float sc = (float)((double)gamma_l[f] / sqrt(var + 1e-5));
    scsh[f]   = sc;
    scsh[H+f] = (float)((double)beta_l[f] - mu*(double)sc);
    sums[f] = 0.0;       // reset for next layer
    sums[H+f] = 0.0;
}

// One block per graph: binary-search sorted batch for the segment; final-layer BN applied
// on the fly: pooled mean of h[r] + relu(xn[r]*sc+sh); then the 3-layer MLP.
__global__ __launch_bounds__(128) void pool_mlp_kernel(const float* __restrict__ h, const float* __restrict__ xn,
        const float* __restrict__ scsh, const int* __restrict__ batch,
        const float* __restrict__ W1, const float* __restrict__ b1,
        const float* __restrict__ W2, const float* __restrict__ b2,
        const float* __restrict__ Wo, const float* __restrict__ bo,
        float* __restrict__ out, int N){
    __shared__ float row[128];
    __shared__ float g1[64];
    __shared__ float g2[32];
    const int g = blockIdx.x;
    const int t = threadIdx.x;
    int lo = 0, hi = N;
    while (lo < hi){ int m = (lo+hi)>>1; if (batch[m] < g) lo = m+1; else hi = m; }
    const int s0 = lo;
    hi = N;
    while (lo < hi){ int m = (lo+hi)>>1; if (batch[m] < g+1) lo = m+1; else hi = m; }
    const int s1 = lo;
    const float sc = scsh[t], sh = scsh[H+t];
    float acc = 0.f;
    for (int r = s0; r < s1; ++r){
        float hv = h[(size_t)r*H + t];
        float xv = xn[(size_t)r*H + t];
        acc += hv + fmaxf(fmaf(xv, sc, sh), 0.f);
    }
    const float inv = 1.0f/fmaxf((float)(s1-s0), 1.0f);
    row[t] = acc*inv;
    __syncthreads();
    if (t < 64){
        float a = b1[t];
        #pragma unroll 4
        for (int i2=0;i2<128;i2++) a = fmaf(row[i2], W1[i2*64+t], a);
        g1[t] = fmaxf(a, 0.f);
    }
    __syncthreads();
    if (t < 32){
        float b = b2[t];
        #pragma unroll 4
        for (int i2=0;i2<64;i2++) b = fmaf(g1[i2], W2[i2*32+t], b);
        g2[t] = fmaxf(b, 0.f);
    }
    __syncthreads();
    if (t < 64){
        float p = (t < 32) ? g2[t]*Wo[t] : 0.f;
        for (int off=32; off>0; off>>=1) p += __shfl_down(p, off);
        if (t == 0) out[g] = p + bo[0];
    }
}

extern "C" void kernel_launch(void* const* d_in, const int* in_sizes, int n_in,
                              void* d_out, int out_size, void* d_ws, size_t ws_size,
                              hipStream_t stream){
    const float* x     = (const float*)d_in[0];
    const int*   eidx  = (const int*)d_in[1];
    const float* eattr = (const float*)d_in[2];
    const int*   batch = (const int*)d_in[3];
    const float* W_emb = (const float*)d_in[4];
    const float* b_emb = (const float*)d_in[5];
    const float* Wf    = (const float*)d_in[6];
    const float* bf    = (const float*)d_in[7];
    const float* Wsm   = (const float*)d_in[8];
    const float* bs    = (const float*)d_in[9];
    const float* gamma = (const float*)d_in[10];
    const float* beta  = (const float*)d_in[11];
    const float* W1    = (const float*)d_in[12];
    const float* b1    = (const float*)d_in[13];
    const float* W2    = (const float*)d_in[14];
    const float* b2    = (const float*)d_in[15];
    const float* Wo    = (const float*)d_in[16];
    const float* bo    = (const float*)d_in[17];
    float* out = (float*)d_out;

    const int N = in_sizes[0]/16;
    const int E = in_sizes[1]/2;
    const int G = out_size;

    const int* srcI = eidx;
    const int* dstI = eidx + E;

    char* p = (char*)d_ws;
    auto alloc = [&](size_t bytes)->char*{ char* r = p; p += (bytes + 255) & ~255ull; return r; };
    float*     h      = (float*)     alloc((size_t)N*H*4);
    float*     xn     = (float*)     alloc((size_t)N*H*4);
    _Float16*  T16    = (_Float16*)  alloc((size_t)N*512*2);
    float*     ea_s   = (float*)     alloc((size_t)E*EFD*4);
    int*       src_s  = (int*)       alloc((size_t)E*4);
    int*       rowptr = (int*)       alloc((size_t)(N+1)*4);
    int*       cursor = (int*)       alloc((size_t)N*4);   // also incl-scan temp
    int*       counts = (int*)       alloc((size_t)N*4);
    int*       bsums  = (int*)       alloc(256*4);
    double*    sums   = (double*)    alloc(2*H*8);
    float*     scsh   = (float*)     alloc(2*H*4);
    s16x8*     bhi    = (s16x8*)     alloc((size_t)NLAYER*8192*16);
    s16x8*     blo    = (s16x8*)     alloc((size_t)NLAYER*8192*16);

    const int thr = 256;
    hipMemsetAsync(counts, 0, (size_t)N*4, stream);
    hipMemsetAsync(sums, 0, 2*H*8, stream);
    embed_kernel<<<(N*H + thr-1)/thr, thr, 0, stream>>>(x, W_emb, b_emb, h, N);
    hist_kernel<<<(E + thr-1)/thr, thr, 0, stream>>>(dstI, counts, E);
    int nb = (N + 1023)/1024;
    scan1<<<nb, 1024, 0, stream>>>(counts, cursor, bsums, N);
    scan2<<<1, 64, 0, stream>>>(bsums, nb);
    scan3<<<nb, 1024, 0, stream>>>(cursor, counts, bsums, rowptr, cursor, N, E);
    scatter_kernel<<<(E + thr-1)/thr, thr, 0, stream>>>(srcI, dstI, eattr, cursor, src_s, ea_s, E);
    wpack_kernel<<<128, 256, 0, stream>>>(Wf, Wsm, bhi, blo);

    const int ntiles = (N + 31)/32;
    for (int l=0;l<NLAYER;l++){
        const float* Wf_l = Wf  + (size_t)l*ZDIM*H;
        const float* Ws_l = Wsm + (size_t)l*ZDIM*H;
        table_mfma<<<512, 512, 0, stream>>>(h, xn, (l==0)?nullptr:scsh, bhi, blo,
                                            bf + l*H, bs + l*H, T16, N, l, ntiles);
        agg_kernel<<<(N+3)/4, 256, 0, stream>>>(T16, rowptr, src_s, ea_s, Wf_l, Ws_l, h, xn, N);
        stats_kernel<<<256, 256, 0, stream>>>(xn, sums, N);
        finalize_bn<<<1, 128, 0, stream>>>(sums, gamma + l*H, beta + l*H, scsh, N);
    }

    pool_mlp_kernel<<<G, 128, 0, stream>>>(h, xn, scsh, batch, W1, b1, W2, b2, Wo, bo, out, N);
}

// Round 11
// 911.983 us; speedup vs baseline: 1.0097x; 1.0097x over previous
//
#include <hip/hip_runtime.h>
#include <hip/hip_bf16.h>

#define H 128
#define EFD 8
#define NLAYER 4
#define ZDIM (2*H+EFD)   // 264

typedef float f32x2 __attribute__((ext_vector_type(2)));
typedef float f32x4 __attribute__((ext_vector_type(4)));
typedef short s16x8 __attribute__((ext_vector_type(8)));
typedef _Float16 f16x4 __attribute__((ext_vector_type(4)));

// packed fp32 fma with src0 broadcast from low/high half (VOP3P op_sel)
#define PKFMA_LO(acc, a, b) asm("v_pk_fma_f32 %0, %1, %2, %0 op_sel:[0,0,0] op_sel_hi:[0,1,1]" : "+v"(acc) : "v"(a), "v"(b))
#define PKFMA_HI(acc, a, b) asm("v_pk_fma_f32 %0, %1, %2, %0 op_sel:[1,0,0] op_sel_hi:[1,1,1]" : "+v"(acc) : "v"(a), "v"(b))
#define PKFMA_LO_INIT(dst, a, b, c) asm("v_pk_fma_f32 %0, %1, %2, %3 op_sel:[0,0,0] op_sel_hi:[0,1,1]" : "=v"(dst) : "v"(a), "v"(b), "v"(c))

#define L2E 1.44269504088896340736f
#define LN2 0.69314718055994530942f

__device__ __forceinline__ unsigned short f2bf(float x){
    unsigned u = __float_as_uint(x);
    return (unsigned short)((u + 0x7FFFu + ((u>>16)&1u)) >> 16);
}

// h = relu(x @ W_emb + b_emb)   [N,16]@[16,128]
__global__ void embed_kernel(const float* __restrict__ x, const float* __restrict__ We,
                             const float* __restrict__ be, float* __restrict__ h, int N){
    int idx = blockIdx.x*blockDim.x + threadIdx.x;
    if (idx >= N*H) return;
    int n = idx >> 7, f = idx & 127;
    float a = be[f];
    #pragma unroll
    for (int k=0;k<16;k++) a = fmaf(x[n*16+k], We[k*H+f], a);
    h[idx] = fmaxf(a, 0.f);
}

__global__ void hist_kernel(const int* __restrict__ dstI, int* __restrict__ counts, int E){
    int e = blockIdx.x*blockDim.x + threadIdx.x;
    if (e < E) atomicAdd(&counts[dstI[e]], 1);
}

__global__ __launch_bounds__(1024) void scan1(const int* __restrict__ counts, int* __restrict__ incl,
                                              int* __restrict__ bsums, int N){
    __shared__ int lds[1024];
    int t = threadIdx.x;
    int i = blockIdx.x*1024 + t;
    int v = (i < N) ? counts[i] : 0;
    lds[t] = v;
    __syncthreads();
    for (int off=1; off<1024; off<<=1){
        int add = (t>=off) ? lds[t-off] : 0;
        __syncthreads();
        lds[t] += add;
        __syncthreads();
    }
    if (i < N) incl[i] = lds[t];
    if (t == 1023) bsums[blockIdx.x] = lds[1023];
}

__global__ void scan2(int* bsums, int nb){
    if (threadIdx.x == 0){
        int run = 0;
        for (int b=0;b<nb;b++){ int v = bsums[b]; bsums[b] = run; run += v; }
    }
}

__global__ __launch_bounds__(1024) void scan3(const int* incl, const int* __restrict__ counts,
                                              const int* __restrict__ bsums, int* __restrict__ rowptr,
                                              int* cursor, int N, int E){
    int i = blockIdx.x*1024 + threadIdx.x;
    if (i >= N) return;
    int ex = incl[i] - counts[i] + bsums[blockIdx.x];
    rowptr[i] = ex;
    cursor[i] = ex;
    if (i == N-1) rowptr[N] = E;
}

__global__ void scatter_kernel(const int* __restrict__ srcI, const int* __restrict__ dstI,
                               const float* __restrict__ eattr, int* __restrict__ cursor,
                               int* __restrict__ src_s, float* __restrict__ ea_s, int E){
    int e = blockIdx.x*blockDim.x + threadIdx.x;
    if (e >= E) return;
    int d = dstI[e];
    int pos = atomicAdd(&cursor[d], 1);
    src_s[pos] = srcI[e];
    const float4* s4 = (const float4*)(eattr + (size_t)e*EFD);
    float4* o4 = (float4*)(ea_s + (size_t)pos*EFD);
    o4[0] = s4[0]; o4[1] = s4[1];
}

// Pack node-part weights (rows 0..255 of Wf/Ws, all 4 layers) into per-lane MFMA B
// fragments, split hi/lo bf16. Index: idx = ((layer*4 + w)*4 + ks)*8*64 + ct*64 + lane.
__global__ __launch_bounds__(256) void wpack_kernel(const float* __restrict__ Wf, const float* __restrict__ Ws,
        s16x8* __restrict__ bhi, s16x8* __restrict__ blo){
    int idx = blockIdx.x*256 + threadIdx.x;   // 32768 total
    int l = idx & 63, ct = (idx>>6)&7, ks = (idx>>9)&3, w = (idx>>11)&3, layer = idx>>13;
    int cp = w*128 + ct*16 + (l&15);
    int k0 = ks*32 + ((l>>4)<<3);
    const float* WfL = Wf + (size_t)layer*ZDIM*H;
    const float* WsL = Ws + (size_t)layer*ZDIM*H;
    int colIn = cp & 127;
    int sel = cp >> 7;
    const float* Wm = (sel & 1) ? WsL : WfL;
    int krow = (sel >> 1) ? H : 0;
    s16x8 vh, vl;
    #pragma unroll
    for (int e=0;e<8;e++){
        float v = Wm[(size_t)(krow + k0 + e)*H + colIn];
        unsigned short hb = f2bf(v);
        float rem = v - __uint_as_float(((unsigned)hb)<<16);
        vh[e] = (short)hb;
        vl[e] = (short)f2bf(rem);
    }
    bhi[idx] = vh;
    blo[idx] = vl;
}

// Persistent [N,128]@[128,512] GEMM, bf16 MFMA 3-term hi/lo split (~fp32 accuracy).
// 256 blocks x 512 threads (8 waves). Wave W owns 64 output cols; its B fragments
// (32 x s16x8 hi+lo) are register-resident, loaded ONCE. Block grid-strides over
// 32-node tiles: stage h-tile (with fused BN from previous layer) into LDS, MFMA,
// write TD (fp32 [Fd|Sd]+bias) / TS16 (fp16 interleaved F2k,F2k+1,S2k,S2k+1).
// Everything pre-scaled by log2(e) for exp2-domain gates.
__global__ __launch_bounds__(512, 2) void table_mfma(
        float* __restrict__ h, const float* __restrict__ xn, const float* __restrict__ scsh,
        const s16x8* __restrict__ bhi, const s16x8* __restrict__ blo,
        const float* __restrict__ bf_l, const float* __restrict__ bs_l,
        float* __restrict__ TD, _Float16* __restrict__ TS16, int N, int layer, int ntiles){
    __shared__ __align__(16) short amat[2][32*136];   // hi/lo, 272B row pitch (2-way bank alias = free)
    const int t = threadIdx.x;
    const int lane = t & 63, W = t >> 6;
    const int ow = W >> 1, ctbase = (W & 1)*4;
    const int rbase = lane & 15, kg = lane >> 4;

    // ---- B fragments: load once, pin in VGPRs ----
    s16x8 Bh[4][4], Bl[4][4];
    {
        const size_t bbase = ((size_t)layer*4 + ow)*2048;
        #pragma unroll
        for (int ks=0;ks<4;ks++)
            #pragma unroll
            for (int c=0;c<4;c++){
                Bh[ks][c] = bhi[bbase + ks*512 + (ctbase+c)*64 + lane];
                Bl[ks][c] = blo[bbase + ks*512 + (ctbase+c)*64 + lane];
            }
        #pragma unroll
        for (int ks=0;ks<4;ks++)
            #pragma unroll
            for (int c=0;c<4;c++) asm volatile("" : "+v"(Bh[ks][c]), "+v"(Bl[ks][c]));
    }
    // ---- per-lane output constants (hoisted) ----
    int c_local[4], off16[4];
    float bv[4];
    #pragma unroll
    for (int c=0;c<4;c++){
        c_local[c] = (ctbase+c)*16 + rbase;
        off16[c] = (c_local[c] >> 1)*4 + ((ow & 1) << 1) + (c_local[c] & 1);
        bv[c] = (ow == 0) ? bf_l[c_local[c]]*L2E : (ow == 1) ? bs_l[c_local[c]]*L2E : 0.f;
    }
    // ---- staging constants ----
    const int srow = t >> 4;          // 0..31
    const int kb = (t & 15)*8;        // 0..120
    float sc8[8], sh8[8];
    if (scsh){
        #pragma unroll
        for (int q=0;q<8;q+=4){
            *(float4*)&sc8[q] = *(const float4*)(scsh + kb + q);
            *(float4*)&sh8[q] = *(const float4*)(scsh + H + kb + q);
        }
    }

    for (int tile = blockIdx.x; tile < ntiles; tile += gridDim.x){
        const int n0 = tile*32;
        {   // ---- stage 32x128 tile (fused BN for layers>0) ----
            const int gn = n0 + srow;
            const bool valid = gn < N;
            float* hr = h + (size_t)gn*H + kb;
            float vv[8];
            if (scsh){
                const float* xr = xn + (size_t)gn*H + kb;
                #pragma unroll
                for (int q=0;q<8;q+=4){
                    float4 xv = valid ? *(const float4*)(xr + q) : make_float4(0.f,0.f,0.f,0.f);
                    float4 hv = valid ? *(const float4*)(hr + q) : make_float4(0.f,0.f,0.f,0.f);
                    vv[q]   = hv.x + fmaxf(fmaf(xv.x, sc8[q],   sh8[q]),   0.f);
                    vv[q+1] = hv.y + fmaxf(fmaf(xv.y, sc8[q+1], sh8[q+1]), 0.f);
                    vv[q+2] = hv.z + fmaxf(fmaf(xv.z, sc8[q+2], sh8[q+2]), 0.f);
                    vv[q+3] = hv.w + fmaxf(fmaf(xv.w, sc8[q+3], sh8[q+3]), 0.f);
                }
                if (valid){
                    #pragma unroll
                    for (int q=0;q<8;q+=4){
                        float4 o; o.x=vv[q]; o.y=vv[q+1]; o.z=vv[q+2]; o.w=vv[q+3];
                        *(float4*)(hr + q) = o;
                    }
                }
            } else {
                #pragma unroll
                for (int q=0;q<8;q+=4){
                    float4 hv = valid ? *(const float4*)(hr + q) : make_float4(0.f,0.f,0.f,0.f);
                    vv[q]=hv.x; vv[q+1]=hv.y; vv[q+2]=hv.z; vv[q+3]=hv.w;
                }
            }
            s16x8 hv2, lv2;
            #pragma unroll
            for (int q=0;q<8;q++){
                unsigned short hb = f2bf(vv[q]);
                float rem = vv[q] - __uint_as_float(((unsigned)hb)<<16);
                hv2[q] = (short)hb;
                lv2[q] = (short)f2bf(rem);
            }
            *(s16x8*)&amat[0][srow*136 + kb] = hv2;
            *(s16x8*)&amat[1][srow*136 + kb] = lv2;
        }
        __syncthreads();
        // ---- MFMA ----
        f32x4 acc[2][4];
        #pragma unroll
        for (int rt=0;rt<2;rt++)
            #pragma unroll
            for (int c=0;c<4;c++){ acc[rt][c][0]=0.f; acc[rt][c][1]=0.f; acc[rt][c][2]=0.f; acc[rt][c][3]=0.f; }
        #pragma unroll
        for (int ks=0;ks<4;ks++){
            s16x8 ah[2], al[2];
            #pragma unroll
            for (int rt=0;rt<2;rt++){
                const int ao = (rbase + 16*rt)*136 + ks*32 + kg*8;
                ah[rt] = *(const s16x8*)&amat[0][ao];
                al[rt] = *(const s16x8*)&amat[1][ao];
            }
            #pragma unroll
            for (int c=0;c<4;c++)
                #pragma unroll
                for (int rt=0;rt<2;rt++){
                    acc[rt][c] = __builtin_amdgcn_mfma_f32_16x16x32_bf16(ah[rt], Bh[ks][c], acc[rt][c], 0, 0, 0);
                    acc[rt][c] = __builtin_amdgcn_mfma_f32_16x16x32_bf16(ah[rt], Bl[ks][c], acc[rt][c], 0, 0, 0);
                    acc[rt][c] = __builtin_amdgcn_mfma_f32_16x16x32_bf16(al[rt], Bh[ks][c], acc[rt][c], 0, 0, 0);
                }
        }
        // ---- write out ----
        if (ow < 2){
            const int colbase = (ow & 1)*128;
            #pragma unroll
            for (int c=0;c<4;c++)
                #pragma unroll
                for (int rt=0;rt<2;rt++){
                    const int nrow0 = n0 + 16*rt + kg*4;
                    #pragma unroll
                    for (int r=0;r<4;r++){
                        const int nd = nrow0 + r;
                        if (nd < N) TD[(size_t)nd*256 + colbase + c_local[c]] = fmaf(acc[rt][c][r], L2E, bv[c]);
                    }
                }
        } else {
            #pragma unroll
            for (int c=0;c<4;c++)
                #pragma unroll
                for (int rt=0;rt<2;rt++){
                    const int nrow0 = n0 + 16*rt + kg*4;
                    #pragma unroll
                    for (int r=0;r<4;r++){
                        const int nd = nrow0 + r;
                        if (nd < N) TS16[(size_t)nd*256 + off16[c]] = (_Float16)(acc[rt][c][r]*L2E);
                    }
                }
        }
        __syncthreads();
    }
}

// One wave per node; weights pinned in VGPRs; packed fp32 fma; exp2-domain gates.
// Src table gathered as fp16 interleaved: one 8B load per lane per edge. (round-5 form)
__global__ __launch_bounds__(256, 4) void agg_kernel(
        const float* __restrict__ TD, const _Float16* __restrict__ TS16,
        const int* __restrict__ rowptr, const int* __restrict__ src_s, const float* __restrict__ ea_s,
        const float* __restrict__ Wf_l, const float* __restrict__ Ws_l,
        const float* __restrict__ h, float* __restrict__ xn, int N){
    __shared__ float wE[2048];   // [8][128] Wf edge rows, then [8][128] Ws edge rows (scaled by log2e)
    const int t = threadIdx.x;
    {
        const float4* a = (const float4*)(Wf_l + 2*H*H);
        const float4* b = (const float4*)(Ws_l + 2*H*H);
        float4 va = a[t], vb = b[t];
        va.x*=L2E; va.y*=L2E; va.z*=L2E; va.w*=L2E;
        vb.x*=L2E; vb.y*=L2E; vb.z*=L2E; vb.w*=L2E;
        ((float4*)wE)[t] = va;
        ((float4*)wE)[256 + t] = vb;
    }
    __syncthreads();
    const int k = t & 63;
    const int i = blockIdx.x*4 + (t >> 6);
    if (i >= N) return;
    f32x2 wef2[8], wes2[8];
    #pragma unroll
    for (int r=0;r<8;r++){
        wef2[r] = *(const f32x2*)&wE[r*128 + 2*k];
        wes2[r] = *(const f32x2*)&wE[1024 + r*128 + 2*k];
    }
    #pragma unroll
    for (int r=0;r<8;r++) asm volatile("" : "+v"(wef2[r]), "+v"(wes2[r]));
    const f32x2* td = (const f32x2*)(TD + ((size_t)i << 8));
    f32x2 fd2 = td[k], sd2 = td[64+k];
    f32x2 acc = {0.f, 0.f};
    const int e0 = __builtin_amdgcn_readfirstlane(rowptr[i]);
    const int e1 = __builtin_amdgcn_readfirstlane(rowptr[i+1]);
    const int myoff = 4*k;
    int j = (e0 < e1) ? __builtin_amdgcn_readfirstlane(src_s[e0]) : 0;
    f16x4 tv = *(const f16x4*)(TS16 + (((size_t)(unsigned)j) << 8) + myoff);
    for (int e = e0; e < e1; ++e){
        const int en = (e+1 < e1) ? (e+1) : e;
        const int jn = __builtin_amdgcn_readfirstlane(src_s[en]);
        f16x4 tvn = *(const f16x4*)(TS16 + (((size_t)(unsigned)jn) << 8) + myoff);
        const float* ep = ea_s + (size_t)e*EFD;
        f32x4 eaA = *(const f32x4*)(ep);
        f32x4 eaB = *(const f32x4*)(ep + 4);
        f32x2 ea0 = __builtin_shufflevector(eaA, eaA, 0, 1);
        f32x2 ea1 = __builtin_shufflevector(eaA, eaA, 2, 3);
        f32x2 ea2 = __builtin_shufflevector(eaB, eaB, 0, 1);
        f32x2 ea3 = __builtin_shufflevector(eaB, eaB, 2, 3);
        f32x2 ef, es;
        PKFMA_LO_INIT(ef, ea0, wef2[0], fd2);
        PKFMA_HI(ef, ea0, wef2[1]);
        PKFMA_LO(ef, ea1, wef2[2]); PKFMA_HI(ef, ea1, wef2[3]);
        PKFMA_LO(ef, ea2, wef2[4]); PKFMA_HI(ef, ea2, wef2[5]);
        PKFMA_LO(ef, ea3, wef2[6]); PKFMA_HI(ef, ea3, wef2[7]);
        PKFMA_LO_INIT(es, ea0, wes2[0], sd2);
        PKFMA_HI(es, ea0, wes2[1]);
        PKFMA_LO(es, ea1, wes2[2]); PKFMA_HI(es, ea1, wes2[3]);
        PKFMA_LO(es, ea2, wes2[4]); PKFMA_HI(es, ea2, wes2[5]);
        PKFMA_LO(es, ea3, wes2[6]); PKFMA_HI(es, ea3, wes2[7]);
        f32x2 g = ef, p = es;
        g.x += (float)tv[0]; g.y += (float)tv[1];
        p.x += (float)tv[2]; p.y += (float)tv[3];
        float sx = __builtin_amdgcn_rcpf(1.0f + __builtin_amdgcn_exp2f(-g.x));
        float sy = __builtin_amdgcn_rcpf(1.0f + __builtin_amdgcn_exp2f(-g.y));
        float tx = fmaxf(p.x, 0.f) + __builtin_amdgcn_logf(1.0f + __builtin_amdgcn_exp2f(-fabsf(p.x)));
        float ty = fmaxf(p.y, 0.f) + __builtin_amdgcn_logf(1.0f + __builtin_amdgcn_exp2f(-fabsf(p.y)));
        acc.x = fmaf(sx*tx, LN2, acc.x);
        acc.y = fmaf(sy*ty, LN2, acc.y);
        tv = tvn; j = jn;
    }
    f32x2 hv = *(const f32x2*)(h + ((size_t)i << 7) + 2*k);
    f32x2 o = acc + hv;
    *(f32x2*)(xn + ((size_t)i << 7) + 2*k) = o;
}

// Stats + fused finalize (last-block-done pattern): block-local fp64 reduction,
// device atomics into sums, then the last finishing block computes scsh and
// resets sums + counter (deterministic across graph replays).
__global__ __launch_bounds__(256) void stats_kernel(const float* __restrict__ xn, double* __restrict__ sums,
        const float* __restrict__ gamma_l, const float* __restrict__ beta_l,
        float* __restrict__ scsh, int* __restrict__ done, int N){
    __shared__ double l1[128], l2[128];
    __shared__ int lastflag;
    const int f = threadIdx.x & 127;
    const int half = threadIdx.x >> 7;
    const int nb = gridDim.x;
    const int per = (N + nb - 1)/nb;
    const int r0 = blockIdx.x*per;
    const int r1 = min(N, r0+per);
    double s = 0.0, s2 = 0.0;
    for (int r=r0+half; r<r1; r+=2){
        float v = xn[(size_t)r*H + f];
        s += v; s2 += (double)v*(double)v;
    }
    if (half == 1){ l1[f] = s; l2[f] = s2; }
    __syncthreads();
    if (half == 0){
        s += l1[f]; s2 += l2[f];
        atomicAdd(&sums[f], s);
        atomicAdd(&sums[H+f], s2);
    }
    __threadfence();
    if (threadIdx.x == 0){
        int prev = atomicAdd(done, 1);
        lastflag = (prev == nb - 1) ? 1 : 0;
    }
    __syncthreads();
    if (lastflag && threadIdx.x < H){
        const int ff = threadIdx.x;
        // atomic reads (fetch-add 0) -> device-scope coherent across XCD L2s
        double su = atomicAdd(&sums[ff], 0.0);
        double sq = atomicAdd(&sums[H+ff], 0.0);
        double mu = su/(double)N;
        double var = sq/(double)N - mu*mu;
        if (var < 0.0) var = 0.0;
        float sc = (float)((double)gamma_l[ff] / sqrt(var + 1e-5));
        scsh[ff]   = sc;
        scsh[H+ff] = (float)((double)beta_l[ff] - mu*(double)sc);
        sums[ff] = 0.0;     // reset for next layer
        sums[H+ff] = 0.0;
        if (ff == 0) *done = 0;
    }
}

// One block per graph: binary-search sorted batch for the segment; final-layer BN applied
// on the fly: pooled mean of h[r] + relu(xn[r]*sc+sh); then the 3-layer MLP.
__global__ __launch_bounds__(128) void pool_mlp_kernel(const float* __restrict__ h, const float* __restrict__ xn,
        const float* __restrict__ scsh, const int* __restrict__ batch,
        const float* __restrict__ W1, const float* __restrict__ b1,
        const float* __restrict__ W2, const float* __restrict__ b2,
        const float* __restrict__ Wo, const float* __restrict__ bo,
        float* __restrict__ out, int N){
    __shared__ float row[128];
    __shared__ float g1[64];
    __shared__ float g2[32];
    const int g = blockIdx.x;
    const int t = threadIdx.x;
    int lo = 0, hi = N;
    while (lo < hi){ int m = (lo+hi)>>1; if (batch[m] < g) lo = m+1; else hi = m; }
    const int s0 = lo;
    hi = N;
    while (lo < hi){ int m = (lo+hi)>>1; if (batch[m] < g+1) lo = m+1; else hi = m; }
    const int s1 = lo;
    const float sc = scsh[t], sh = scsh[H+t];
    float acc = 0.f;
    for (int r = s0; r < s1; ++r){
        float hv = h[(size_t)r*H + t];
        float xv = xn[(size_t)r*H + t];
        acc += hv + fmaxf(fmaf(xv, sc, sh), 0.f);
    }
    const float inv = 1.0f/fmaxf((float)(s1-s0), 1.0f);
    row[t] = acc*inv;
    __syncthreads();
    if (t < 64){
        float a = b1[t];
        #pragma unroll 4
        for (int i2=0;i2<128;i2++) a = fmaf(row[i2], W1[i2*64+t], a);
        g1[t] = fmaxf(a, 0.f);
    }
    __syncthreads();
    if (t < 32){
        float b = b2[t];
        #pragma unroll 4
        for (int i2=0;i2<64;i2++) b = fmaf(g1[i2], W2[i2*32+t], b);
        g2[t] = fmaxf(b, 0.f);
    }
    __syncthreads();
    if (t < 64){
        float p = (t < 32) ? g2[t]*Wo[t] : 0.f;
        for (int off=32; off>0; off>>=1) p += __shfl_down(p, off);
        if (t == 0) out[g] = p + bo[0];
    }
}

extern "C" void kernel_launch(void* const* d_in, const int* in_sizes, int n_in,
                              void* d_out, int out_size, void* d_ws, size_t ws_size,
                              hipStream_t stream){
    const float* x     = (const float*)d_in[0];
    const int*   eidx  = (const int*)d_in[1];
    const float* eattr = (const float*)d_in[2];
    const int*   batch = (const int*)d_in[3];
    const float* W_emb = (const float*)d_in[4];
    const float* b_emb = (const float*)d_in[5];
    const float* Wf    = (const float*)d_in[6];
    const float* bf    = (const float*)d_in[7];
    const float* Wsm   = (const float*)d_in[8];
    const float* bs    = (const float*)d_in[9];
    const float* gamma = (const float*)d_in[10];
    const float* beta  = (const float*)d_in[11];
    const float* W1    = (const float*)d_in[12];
    const float* b1    = (const float*)d_in[13];
    const float* W2    = (const float*)d_in[14];
    const float* b2    = (const float*)d_in[15];
    const float* Wo    = (const float*)d_in[16];
    const float* bo    = (const float*)d_in[17];
    float* out = (float*)d_out;

    const int N = in_sizes[0]/16;
    const int E = in_sizes[1]/2;
    const int G = out_size;

    const int* srcI = eidx;
    const int* dstI = eidx + E;

    char* p = (char*)d_ws;
    auto alloc = [&](size_t bytes)->char*{ char* r = p; p += (bytes + 255) & ~255ull; return r; };
    float*     h      = (float*)     alloc((size_t)N*H*4);
    float*     xn     = (float*)     alloc((size_t)N*H*4);
    float*     TD     = (float*)     alloc((size_t)N*2*H*4);
    _Float16*  TS16   = (_Float16*)  alloc((size_t)N*2*H*2);
    float*     ea_s   = (float*)     alloc((size_t)E*EFD*4);
    int*       src_s  = (int*)       alloc((size_t)E*4);
    int*       rowptr = (int*)       alloc((size_t)(N+1)*4);
    int*       cursor = (int*)       alloc((size_t)N*4);   // also incl-scan temp
    int*       counts = (int*)       alloc((size_t)N*4);
    int*       bsums  = (int*)       alloc(256*4);
    double*    sums   = (double*)    alloc(2*H*8);
    float*     scsh   = (float*)     alloc(2*H*4);
    int*       done   = (int*)       alloc(256);
    s16x8*     bhi    = (s16x8*)     alloc((size_t)NLAYER*8192*16);
    s16x8*     blo    = (s16x8*)     alloc((size_t)NLAYER*8192*16);

    const int thr = 256;
    hipMemsetAsync(counts, 0, (size_t)N*4, stream);
    hipMemsetAsync(sums, 0, 2*H*8, stream);
    hipMemsetAsync(done, 0, 256, stream);
    embed_kernel<<<(N*H + thr-1)/thr, thr, 0, stream>>>(x, W_emb, b_emb, h, N);
    hist_kernel<<<(E + thr-1)/thr, thr, 0, stream>>>(dstI, counts, E);
    int nb = (N + 1023)/1024;
    scan1<<<nb, 1024, 0, stream>>>(counts, cursor, bsums, N);
    scan2<<<1, 64, 0, stream>>>(bsums, nb);
    scan3<<<nb, 1024, 0, stream>>>(cursor, counts, bsums, rowptr, cursor, N, E);
    scatter_kernel<<<(E + thr-1)/thr, thr, 0, stream>>>(srcI, dstI, eattr, cursor, src_s, ea_s, E);
    wpack_kernel<<<128, 256, 0, stream>>>(Wf, Wsm, bhi, blo);

    const int ntiles = (N + 31)/32;
    for (int l=0;l<NLAYER;l++){
        const float* Wf_l = Wf  + (size_t)l*ZDIM*H;
        const float* Ws_l = Wsm + (size_t)l*ZDIM*H;
        table_mfma<<<256, 512, 0, stream>>>(h, xn, (l==0)?nullptr:scsh, bhi, blo,
                                            bf + l*H, bs + l*H, TD, TS16, N, l, ntiles);
        agg_kernel<<<(N+3)/4, 256, 0, stream>>>(TD, TS16, rowptr, src_s, ea_s, Wf_l, Ws_l, h, xn, N);
        stats_kernel<<<256, 256, 0, stream>>>(xn, sums, gamma + l*H, beta + l*H, scsh, done, N);
    }

    pool_mlp_kernel<<<G, 128, 0, stream>>>(h, xn, scsh, batch, W1, b1, W2, b2, Wo, bo, out, N);
}

// Round 12
// 848.508 us; speedup vs baseline: 1.0852x; 1.0748x over previous
//
#include <hip/hip_runtime.h>
#include <hip/hip_bf16.h>

#define H 128
#define EFD 8
#define NLAYER 4
#define ZDIM (2*H+EFD)   // 264

typedef float f32x2 __attribute__((ext_vector_type(2)));
typedef float f32x4 __attribute__((ext_vector_type(4)));
typedef short s16x8 __attribute__((ext_vector_type(8)));
typedef _Float16 f16x4 __attribute__((ext_vector_type(4)));
typedef unsigned int u32x2 __attribute__((ext_vector_type(2)));

// packed fp32 fma with src0 broadcast from low/high half (VOP3P op_sel)
#define PKFMA_LO(acc, a, b) asm("v_pk_fma_f32 %0, %1, %2, %0 op_sel:[0,0,0] op_sel_hi:[0,1,1]" : "+v"(acc) : "v"(a), "v"(b))
#define PKFMA_HI(acc, a, b) asm("v_pk_fma_f32 %0, %1, %2, %0 op_sel:[1,0,0] op_sel_hi:[1,1,1]" : "+v"(acc) : "v"(a), "v"(b))
#define PKFMA_LO_INIT(dst, a, b, c) asm("v_pk_fma_f32 %0, %1, %2, %3 op_sel:[0,0,0] op_sel_hi:[0,1,1]" : "=v"(dst) : "v"(a), "v"(b), "v"(c))
// D.f32 = f16(src0 half) * 1.0 + src2.f32   (exact fp16->fp32 convert-and-add)
#define FMAMIX_LO(dst, h2, add) asm("v_fma_mix_f32 %0, %1, 1.0, %2 op_sel:[0,0,0] op_sel_hi:[1,0,0]" : "=v"(dst) : "v"(h2), "v"(add))
#define FMAMIX_HI(dst, h2, add) asm("v_fma_mix_f32 %0, %1, 1.0, %2 op_sel:[1,0,0] op_sel_hi:[1,0,0]" : "=v"(dst) : "v"(h2), "v"(add))

#define L2E 1.44269504088896340736f
#define LN2 0.69314718055994530942f

__device__ __forceinline__ unsigned short f2bf(float x){
    unsigned u = __float_as_uint(x);
    return (unsigned short)((u + 0x7FFFu + ((u>>16)&1u)) >> 16);
}

// h = relu(x @ W_emb + b_emb)   [N,16]@[16,128]
__global__ void embed_kernel(const float* __restrict__ x, const float* __restrict__ We,
                             const float* __restrict__ be, float* __restrict__ h, int N){
    int idx = blockIdx.x*blockDim.x + threadIdx.x;
    if (idx >= N*H) return;
    int n = idx >> 7, f = idx & 127;
    float a = be[f];
    #pragma unroll
    for (int k=0;k<16;k++) a = fmaf(x[n*16+k], We[k*H+f], a);
    h[idx] = fmaxf(a, 0.f);
}

__global__ void hist_kernel(const int* __restrict__ dstI, int* __restrict__ counts, int E){
    int e = blockIdx.x*blockDim.x + threadIdx.x;
    if (e < E) atomicAdd(&counts[dstI[e]], 1);
}

__global__ __launch_bounds__(1024) void scan1(const int* __restrict__ counts, int* __restrict__ incl,
                                              int* __restrict__ bsums, int N){
    __shared__ int lds[1024];
    int t = threadIdx.x;
    int i = blockIdx.x*1024 + t;
    int v = (i < N) ? counts[i] : 0;
    lds[t] = v;
    __syncthreads();
    for (int off=1; off<1024; off<<=1){
        int add = (t>=off) ? lds[t-off] : 0;
        __syncthreads();
        lds[t] += add;
        __syncthreads();
    }
    if (i < N) incl[i] = lds[t];
    if (t == 1023) bsums[blockIdx.x] = lds[1023];
}

// single-wave shfl exclusive scan (nb <= 64 fast path; serial fallback otherwise)
__global__ __launch_bounds__(64) void scan2(int* bsums, int nb){
    int t = threadIdx.x;
    if (nb <= 64){
        int orig = (t < nb) ? bsums[t] : 0;
        int v = orig;
        for (int off=1; off<64; off<<=1){
            int n = __shfl_up(v, off);
            if (t >= off) v += n;
        }
        if (t < nb) bsums[t] = v - orig;
    } else if (t == 0){
        int run = 0;
        for (int b=0;b<nb;b++){ int v = bsums[b]; bsums[b] = run; run += v; }
    }
}

__global__ __launch_bounds__(1024) void scan3(const int* incl, const int* __restrict__ counts,
                                              const int* __restrict__ bsums, int* __restrict__ rowptr,
                                              int* cursor, int N, int E){
    int i = blockIdx.x*1024 + threadIdx.x;
    if (i >= N) return;
    int ex = incl[i] - counts[i] + bsums[blockIdx.x];
    rowptr[i] = ex;
    cursor[i] = ex;
    if (i == N-1) rowptr[N] = E;
}

__global__ void scatter_kernel(const int* __restrict__ srcI, const int* __restrict__ dstI,
                               const float* __restrict__ eattr, int* __restrict__ cursor,
                               int* __restrict__ src_s, float* __restrict__ ea_s, int E){
    int e = blockIdx.x*blockDim.x + threadIdx.x;
    if (e >= E) return;
    int d = dstI[e];
    int pos = atomicAdd(&cursor[d], 1);
    src_s[pos] = srcI[e];
    const float4* s4 = (const float4*)(eattr + (size_t)e*EFD);
    float4* o4 = (float4*)(ea_s + (size_t)pos*EFD);
    o4[0] = s4[0]; o4[1] = s4[1];
}

// Pack node-part weights (rows 0..255 of Wf/Ws, all 4 layers) into per-lane MFMA B
// fragments, split hi/lo bf16. Index: idx = ((layer*4 + w)*4 + ks)*8*64 + ct*64 + lane.
__global__ __launch_bounds__(256) void wpack_kernel(const float* __restrict__ Wf, const float* __restrict__ Ws,
        s16x8* __restrict__ bhi, s16x8* __restrict__ blo){
    int idx = blockIdx.x*256 + threadIdx.x;   // 32768 total
    int l = idx & 63, ct = (idx>>6)&7, ks = (idx>>9)&3, w = (idx>>11)&3, layer = idx>>13;
    int cp = w*128 + ct*16 + (l&15);
    int k0 = ks*32 + ((l>>4)<<3);
    const float* WfL = Wf + (size_t)layer*ZDIM*H;
    const float* WsL = Ws + (size_t)layer*ZDIM*H;
    int colIn = cp & 127;
    int sel = cp >> 7;
    const float* Wm = (sel & 1) ? WsL : WfL;
    int krow = (sel >> 1) ? H : 0;
    s16x8 vh, vl;
    #pragma unroll
    for (int e=0;e<8;e++){
        float v = Wm[(size_t)(krow + k0 + e)*H + colIn];
        unsigned short hb = f2bf(v);
        float rem = v - __uint_as_float(((unsigned)hb)<<16);
        vh[e] = (short)hb;
        vl[e] = (short)f2bf(rem);
    }
    bhi[idx] = vh;
    blo[idx] = vl;
}

// Persistent [N,128]@[128,512] GEMM, bf16 MFMA 3-term hi/lo split (~fp32 accuracy).
// 256 blocks x 512 threads (8 waves). Wave W owns 64 output cols; register-resident B.
// Fused BN-apply (layers>0): h += relu(xn*sc+sh) in-place. Outputs: TD fp32 [Fd|Sd]+bias,
// TS16 fp16 interleaved {F2k,F2k+1,S2k,S2k+1}. Pre-scaled by log2(e).
__global__ __launch_bounds__(512, 2) void table_mfma(
        float* __restrict__ h, const float* __restrict__ xn, const float* __restrict__ scsh,
        const s16x8* __restrict__ bhi, const s16x8* __restrict__ blo,
        const float* __restrict__ bf_l, const float* __restrict__ bs_l,
        float* __restrict__ TD, _Float16* __restrict__ TS16, int N, int layer, int ntiles){
    __shared__ __align__(16) short amat[2][32*136];   // hi/lo, 272B row pitch (2-way bank alias = free)
    const int t = threadIdx.x;
    const int lane = t & 63, W = t >> 6;
    const int ow = W >> 1, ctbase = (W & 1)*4;
    const int rbase = lane & 15, kg = lane >> 4;

    s16x8 Bh[4][4], Bl[4][4];
    {
        const size_t bbase = ((size_t)layer*4 + ow)*2048;
        #pragma unroll
        for (int ks=0;ks<4;ks++)
            #pragma unroll
            for (int c=0;c<4;c++){
                Bh[ks][c] = bhi[bbase + ks*512 + (ctbase+c)*64 + lane];
                Bl[ks][c] = blo[bbase + ks*512 + (ctbase+c)*64 + lane];
            }
        #pragma unroll
        for (int ks=0;ks<4;ks++)
            #pragma unroll
            for (int c=0;c<4;c++) asm volatile("" : "+v"(Bh[ks][c]), "+v"(Bl[ks][c]));
    }
    int c_local[4], off16[4];
    float bv[4];
    #pragma unroll
    for (int c=0;c<4;c++){
        c_local[c] = (ctbase+c)*16 + rbase;
        off16[c] = (c_local[c] >> 1)*4 + ((ow & 1) << 1) + (c_local[c] & 1);
        bv[c] = (ow == 0) ? bf_l[c_local[c]]*L2E : (ow == 1) ? bs_l[c_local[c]]*L2E : 0.f;
    }
    const int srow = t >> 4;          // 0..31
    const int kb = (t & 15)*8;        // 0..120
    float sc8[8], sh8[8];
    if (scsh){
        #pragma unroll
        for (int q=0;q<8;q+=4){
            *(float4*)&sc8[q] = *(const float4*)(scsh + kb + q);
            *(float4*)&sh8[q] = *(const float4*)(scsh + H + kb + q);
        }
    }

    for (int tile = blockIdx.x; tile < ntiles; tile += gridDim.x){
        const int n0 = tile*32;
        {
            const int gn = n0 + srow;
            const bool valid = gn < N;
            float* hr = h + (size_t)gn*H + kb;
            float vv[8];
            if (scsh){
                const float* xr = xn + (size_t)gn*H + kb;
                #pragma unroll
                for (int q=0;q<8;q+=4){
                    float4 xv = valid ? *(const float4*)(xr + q) : make_float4(0.f,0.f,0.f,0.f);
                    float4 hv = valid ? *(const float4*)(hr + q) : make_float4(0.f,0.f,0.f,0.f);
                    vv[q]   = hv.x + fmaxf(fmaf(xv.x, sc8[q],   sh8[q]),   0.f);
                    vv[q+1] = hv.y + fmaxf(fmaf(xv.y, sc8[q+1], sh8[q+1]), 0.f);
                    vv[q+2] = hv.z + fmaxf(fmaf(xv.z, sc8[q+2], sh8[q+2]), 0.f);
                    vv[q+3] = hv.w + fmaxf(fmaf(xv.w, sc8[q+3], sh8[q+3]), 0.f);
                }
                if (valid){
                    #pragma unroll
                    for (int q=0;q<8;q+=4){
                        float4 o; o.x=vv[q]; o.y=vv[q+1]; o.z=vv[q+2]; o.w=vv[q+3];
                        *(float4*)(hr + q) = o;
                    }
                }
            } else {
                #pragma unroll
                for (int q=0;q<8;q+=4){
                    float4 hv = valid ? *(const float4*)(hr + q) : make_float4(0.f,0.f,0.f,0.f);
                    vv[q]=hv.x; vv[q+1]=hv.y; vv[q+2]=hv.z; vv[q+3]=hv.w;
                }
            }
            s16x8 hv2, lv2;
            #pragma unroll
            for (int q=0;q<8;q++){
                unsigned short hb = f2bf(vv[q]);
                float rem = vv[q] - __uint_as_float(((unsigned)hb)<<16);
                hv2[q] = (short)hb;
                lv2[q] = (short)f2bf(rem);
            }
            *(s16x8*)&amat[0][srow*136 + kb] = hv2;
            *(s16x8*)&amat[1][srow*136 + kb] = lv2;
        }
        __syncthreads();
        f32x4 acc[2][4];
        #pragma unroll
        for (int rt=0;rt<2;rt++)
            #pragma unroll
            for (int c=0;c<4;c++){ acc[rt][c][0]=0.f; acc[rt][c][1]=0.f; acc[rt][c][2]=0.f; acc[rt][c][3]=0.f; }
        #pragma unroll
        for (int ks=0;ks<4;ks++){
            s16x8 ah[2], al[2];
            #pragma unroll
            for (int rt=0;rt<2;rt++){
                const int ao = (rbase + 16*rt)*136 + ks*32 + kg*8;
                ah[rt] = *(const s16x8*)&amat[0][ao];
                al[rt] = *(const s16x8*)&amat[1][ao];
            }
            #pragma unroll
            for (int c=0;c<4;c++)
                #pragma unroll
                for (int rt=0;rt<2;rt++){
                    acc[rt][c] = __builtin_amdgcn_mfma_f32_16x16x32_bf16(ah[rt], Bh[ks][c], acc[rt][c], 0, 0, 0);
                    acc[rt][c] = __builtin_amdgcn_mfma_f32_16x16x32_bf16(ah[rt], Bl[ks][c], acc[rt][c], 0, 0, 0);
                    acc[rt][c] = __builtin_amdgcn_mfma_f32_16x16x32_bf16(al[rt], Bh[ks][c], acc[rt][c], 0, 0, 0);
                }
        }
        if (ow < 2){
            const int colbase = (ow & 1)*128;
            #pragma unroll
            for (int c=0;c<4;c++)
                #pragma unroll
                for (int rt=0;rt<2;rt++){
                    const int nrow0 = n0 + 16*rt + kg*4;
                    #pragma unroll
                    for (int r=0;r<4;r++){
                        const int nd = nrow0 + r;
                        if (nd < N) TD[(size_t)nd*256 + colbase + c_local[c]] = fmaf(acc[rt][c][r], L2E, bv[c]);
                    }
                }
        } else {
            #pragma unroll
            for (int c=0;c<4;c++)
                #pragma unroll
                for (int rt=0;rt<2;rt++){
                    const int nrow0 = n0 + 16*rt + kg*4;
                    #pragma unroll
                    for (int r=0;r<4;r++){
                        const int nd = nrow0 + r;
                        if (nd < N) TS16[(size_t)nd*256 + off16[c]] = (_Float16)(acc[rt][c][r]*L2E);
                    }
                }
        }
        __syncthreads();
    }
}

// One wave per node; weights in LDS->regs; packed fp32 fma; exp2-domain gates.
// Unroll-by-2 software pipeline with alternating tv registers (no vector movs):
// ids prefetched one iteration ahead of their gather; gathers one iteration ahead of use.
// fp16 src values folded via v_fma_mix_f32 (exact convert-and-add).
__global__ __launch_bounds__(256, 4) void agg_kernel(
        const float* __restrict__ TD, const _Float16* __restrict__ TS16,
        const int* __restrict__ rowptr, const int* __restrict__ src_s, const float* __restrict__ ea_s,
        const float* __restrict__ Wf_l, const float* __restrict__ Ws_l,
        const float* __restrict__ h, float* __restrict__ xn, int N){
    __shared__ float wE[2048];   // [8][128] Wf edge rows, then [8][128] Ws edge rows (scaled by log2e)
    const int t = threadIdx.x;
    {
        const float4* a = (const float4*)(Wf_l + 2*H*H);
        const float4* b = (const float4*)(Ws_l + 2*H*H);
        float4 va = a[t], vb = b[t];
        va.x*=L2E; va.y*=L2E; va.z*=L2E; va.w*=L2E;
        vb.x*=L2E; vb.y*=L2E; vb.z*=L2E; vb.w*=L2E;
        ((float4*)wE)[t] = va;
        ((float4*)wE)[256 + t] = vb;
    }
    __syncthreads();
    const int k = t & 63;
    const int i = blockIdx.x*4 + (t >> 6);
    if (i >= N) return;
    f32x2 wef2[8], wes2[8];
    #pragma unroll
    for (int r=0;r<8;r++){
        wef2[r] = *(const f32x2*)&wE[r*128 + 2*k];
        wes2[r] = *(const f32x2*)&wE[1024 + r*128 + 2*k];
    }
    #pragma unroll
    for (int r=0;r<8;r++) asm volatile("" : "+v"(wef2[r]), "+v"(wes2[r]));
    const f32x2* td = (const f32x2*)(TD + ((size_t)i << 8));
    f32x2 fd2 = td[k], sd2 = td[64+k];
    f32x2 acc = {0.f, 0.f};
    const int e0 = __builtin_amdgcn_readfirstlane(rowptr[i]);
    const int e1 = __builtin_amdgcn_readfirstlane(rowptr[i+1]);
    const int myoff = 4*k;
    const int last = e1 - 1;

    auto JID = [&](int e)->int {
        int ec = (e <= last) ? e : last;
        return __builtin_amdgcn_readfirstlane(src_s[ec]);
    };
    auto GATHER = [&](int j)->f16x4 {
        return *(const f16x4*)(TS16 + (((size_t)(unsigned)j) << 8) + myoff);
    };
    auto BODY = [&](int e, f16x4 tv){
        const float* ep = ea_s + (size_t)e*EFD;
        f32x4 eaA = *(const f32x4*)(ep);
        f32x4 eaB = *(const f32x4*)(ep + 4);
        f32x2 ea0 = __builtin_shufflevector(eaA, eaA, 0, 1);
        f32x2 ea1 = __builtin_shufflevector(eaA, eaA, 2, 3);
        f32x2 ea2 = __builtin_shufflevector(eaB, eaB, 0, 1);
        f32x2 ea3 = __builtin_shufflevector(eaB, eaB, 2, 3);
        f32x2 ef, es;
        PKFMA_LO_INIT(ef, ea0, wef2[0], fd2);
        PKFMA_HI(ef, ea0, wef2[1]);
        PKFMA_LO(ef, ea1, wef2[2]); PKFMA_HI(ef, ea1, wef2[3]);
        PKFMA_LO(ef, ea2, wef2[4]); PKFMA_HI(ef, ea2, wef2[5]);
        PKFMA_LO(ef, ea3, wef2[6]); PKFMA_HI(ef, ea3, wef2[7]);
        PKFMA_LO_INIT(es, ea0, wes2[0], sd2);
        PKFMA_HI(es, ea0, wes2[1]);
        PKFMA_LO(es, ea1, wes2[2]); PKFMA_HI(es, ea1, wes2[3]);
        PKFMA_LO(es, ea2, wes2[4]); PKFMA_HI(es, ea2, wes2[5]);
        PKFMA_LO(es, ea3, wes2[6]); PKFMA_HI(es, ea3, wes2[7]);
        u32x2 tu = *(u32x2*)&tv;
        float gx, gy, px, py;
        FMAMIX_LO(gx, tu.x, ef.x);
        FMAMIX_HI(gy, tu.x, ef.y);
        FMAMIX_LO(px, tu.y, es.x);
        FMAMIX_HI(py, tu.y, es.y);
        float sx = __builtin_amdgcn_rcpf(1.0f + __builtin_amdgcn_exp2f(-gx));
        float sy = __builtin_amdgcn_rcpf(1.0f + __builtin_amdgcn_exp2f(-gy));
        float tx = fmaxf(px, 0.f) + __builtin_amdgcn_logf(1.0f + __builtin_amdgcn_exp2f(-fabsf(px)));
        float ty = fmaxf(py, 0.f) + __builtin_amdgcn_logf(1.0f + __builtin_amdgcn_exp2f(-fabsf(py)));
        acc.x = fmaf(sx*tx, LN2, acc.x);
        acc.y = fmaf(sy*ty, LN2, acc.y);
    };

    if (e0 < e1){
        int j0 = JID(e0);
        int j1 = JID(e0+1);
        f16x4 tvA = GATHER(j0);
        f16x4 tvB = GATHER(j1);
        int jA = JID(e0+2);     // id for edge e+2 (gathered into tvA after BODY(e))
        int jB = JID(e0+3);     // id for edge e+3
        int e = e0;
        for (; e + 1 < e1; e += 2){
            int jA2 = JID(e+4);
            BODY(e, tvA);
            tvA = GATHER(jA);   // data for e+2, consumed next iteration
            int jB2 = JID(e+5);
            BODY(e+1, tvB);
            tvB = GATHER(jB);   // data for e+3
            jA = jA2; jB = jB2;
        }
        if (e < e1) BODY(e, tvA);
    }
    f32x2 hv = *(const f32x2*)(h + ((size_t)i << 7) + 2*k);
    f32x2 o = acc + hv;
    *(f32x2*)(xn + ((size_t)i << 7) + 2*k) = o;
}

__global__ __launch_bounds__(256) void stats_kernel(const float* __restrict__ xn, double* __restrict__ sums, int N){
    __shared__ double l1[128], l2[128];
    const int f = threadIdx.x & 127;
    const int half = threadIdx.x >> 7;
    const int nb = gridDim.x;
    const int per = (N + nb - 1)/nb;
    const int r0 = blockIdx.x*per;
    const int r1 = min(N, r0+per);
    double s = 0.0, s2 = 0.0;
    for (int r=r0+half; r<r1; r+=2){
        float v = xn[(size_t)r*H + f];
        s += v; s2 += (double)v*(double)v;
    }
    if (half == 1){ l1[f] = s; l2[f] = s2; }
    __syncthreads();
    if (half == 0){
        s += l1[f]; s2 += l2[f];
        atomicAdd(&sums[f], s);
        atomicAdd(&sums[H+f], s2);
    }
}

__global__ void finalize_bn(double* __restrict__ sums, const float* __restrict__ gamma_l,
                            const float* __restrict__ beta_l, float* __restrict__ scsh, int N){
    int f = threadIdx.x;
    if (f >= H) return;
    double mu = sums[f]/(double)N;
    double var = sums[H+f]/(double)N - mu*mu;
    if (var < 0.0) var = 0.0;
    float sc = (float)((double)gamma_l[f] / sqrt(var + 1e-5));
    scsh[f]   = sc;
    scsh[H+f] = (float)((double)beta_l[f] - mu*(double)sc);
    sums[f] = 0.0;       // reset for next layer
    sums[H+f] = 0.0;
}

// One block per graph: binary-search sorted batch for the segment; final-layer BN applied
// on the fly: pooled mean of h[r] + relu(xn[r]*sc+sh); then the 3-layer MLP.
__global__ __launch_bounds__(128) void pool_mlp_kernel(const float* __restrict__ h, const float* __restrict__ xn,
        const float* __restrict__ scsh, const int* __restrict__ batch,
        const float* __restrict__ W1, const float* __restrict__ b1,
        const float* __restrict__ W2, const float* __restrict__ b2,
        const float* __restrict__ Wo, const float* __restrict__ bo,
        float* __restrict__ out, int N){
    __shared__ float row[128];
    __shared__ float g1[64];
    __shared__ float g2[32];
    const int g = blockIdx.x;
    const int t = threadIdx.x;
    int lo = 0, hi = N;
    while (lo < hi){ int m = (lo+hi)>>1; if (batch[m] < g) lo = m+1; else hi = m; }
    const int s0 = lo;
    hi = N;
    while (lo < hi){ int m = (lo+hi)>>1; if (batch[m] < g+1) lo = m+1; else hi = m; }
    const int s1 = lo;
    const float sc = scsh[t], sh = scsh[H+t];
    float acc = 0.f;
    for (int r = s0; r < s1; ++r){
        float hv = h[(size_t)r*H + t];
        float xv = xn[(size_t)r*H + t];
        acc += hv + fmaxf(fmaf(xv, sc, sh), 0.f);
    }
    const float inv = 1.0f/fmaxf((float)(s1-s0), 1.0f);
    row[t] = acc*inv;
    __syncthreads();
    if (t < 64){
        float a = b1[t];
        #pragma unroll 4
        for (int i2=0;i2<128;i2++) a = fmaf(row[i2], W1[i2*64+t], a);
        g1[t] = fmaxf(a, 0.f);
    }
    __syncthreads();
    if (t < 32){
        float b = b2[t];
        #pragma unroll 4
        for (int i2=0;i2<64;i2++) b = fmaf(g1[i2], W2[i2*32+t], b);
        g2[t] = fmaxf(b, 0.f);
    }
    __syncthreads();
    if (t < 64){
        float p = (t < 32) ? g2[t]*Wo[t] : 0.f;
        for (int off=32; off>0; off>>=1) p += __shfl_down(p, off);
        if (t == 0) out[g] = p + bo[0];
    }
}

extern "C" void kernel_launch(void* const* d_in, const int* in_sizes, int n_in,
                              void* d_out, int out_size, void* d_ws, size_t ws_size,
                              hipStream_t stream){
    const float* x     = (const float*)d_in[0];
    const int*   eidx  = (const int*)d_in[1];
    const float* eattr = (const float*)d_in[2];
    const int*   batch = (const int*)d_in[3];
    const float* W_emb = (const float*)d_in[4];
    const float* b_emb = (const float*)d_in[5];
    const float* Wf    = (const float*)d_in[6];
    const float* bf    = (const float*)d_in[7];
    const float* Wsm   = (const float*)d_in[8];
    const float* bs    = (const float*)d_in[9];
    const float* gamma = (const float*)d_in[10];
    const float* beta  = (const float*)d_in[11];
    const float* W1    = (const float*)d_in[12];
    const float* b1    = (const float*)d_in[13];
    const float* W2    = (const float*)d_in[14];
    const float* b2    = (const float*)d_in[15];
    const float* Wo    = (const float*)d_in[16];
    const float* bo    = (const float*)d_in[17];
    float* out = (float*)d_out;

    const int N = in_sizes[0]/16;
    const int E = in_sizes[1]/2;
    const int G = out_size;

    const int* srcI = eidx;
    const int* dstI = eidx + E;

    char* p = (char*)d_ws;
    auto alloc = [&](size_t bytes)->char*{ char* r = p; p += (bytes + 255) & ~255ull; return r; };
    float*     h      = (float*)     alloc((size_t)N*H*4);
    float*     xn     = (float*)     alloc((size_t)N*H*4);
    float*     TD     = (float*)     alloc((size_t)N*2*H*4);
    _Float16*  TS16   = (_Float16*)  alloc((size_t)N*2*H*2);
    float*     ea_s   = (float*)     alloc((size_t)E*EFD*4);
    int*       src_s  = (int*)       alloc((size_t)E*4);
    int*       rowptr = (int*)       alloc((size_t)(N+1)*4);
    int*       cursor = (int*)       alloc((size_t)N*4);   // also incl-scan temp
    int*       counts = (int*)       alloc((size_t)N*4);
    int*       bsums  = (int*)       alloc(256*4);
    double*    sums   = (double*)    alloc(2*H*8);
    float*     scsh   = (float*)     alloc(2*H*4);
    s16x8*     bhi    = (s16x8*)     alloc((size_t)NLAYER*8192*16);
    s16x8*     blo    = (s16x8*)     alloc((size_t)NLAYER*8192*16);

    const int thr = 256;
    hipMemsetAsync(counts, 0, (size_t)N*4, stream);
    hipMemsetAsync(sums, 0, 2*H*8, stream);
    embed_kernel<<<(N*H + thr-1)/thr, thr, 0, stream>>>(x, W_emb, b_emb, h, N);
    hist_kernel<<<(E + thr-1)/thr, thr, 0, stream>>>(dstI, counts, E);
    int nb = (N + 1023)/1024;
    scan1<<<nb, 1024, 0, stream>>>(counts, cursor, bsums, N);
    scan2<<<1, 64, 0, stream>>>(bsums, nb);
    scan3<<<nb, 1024, 0, stream>>>(cursor, counts, bsums, rowptr, cursor, N, E);
    scatter_kernel<<<(E + thr-1)/thr, thr, 0, stream>>>(srcI, dstI, eattr, cursor, src_s, ea_s, E);
    wpack_kernel<<<128, 256, 0, stream>>>(Wf, Wsm, bhi, blo);

    const int ntiles = (N + 31)/32;
    for (int l=0;l<NLAYER;l++){
        table_mfma<<<256, 512, 0, stream>>>(h, xn, (l==0)?nullptr:scsh, bhi, blo,
                                            bf + l*H, bs + l*H, TD, TS16, N, l, ntiles);
        agg_kernel<<<(N+3)/4, 256, 0, stream>>>(TD, TS16, rowptr, src_s, ea_s,
                                                Wf + (size_t)l*ZDIM*H, Wsm + (size_t)l*ZDIM*H, h, xn, N);
        stats_kernel<<<256, 256, 0, stream>>>(xn, sums, N);
        finalize_bn<<<1, 128, 0, stream>>>(sums, gamma + l*H, beta + l*H, scsh, N);
    }

    pool_mlp_kernel<<<G, 128, 0, stream>>>(h, xn, scsh, batch, W1, b1, W2, b2, Wo, bo, out, N);
}

// Round 14
// 832.500 us; speedup vs baseline: 1.1061x; 1.0192x over previous
//
#include <hip/hip_runtime.h>
#include <hip/hip_bf16.h>

#define H 128
#define EFD 8
#define NLAYER 4
#define ZDIM (2*H+EFD)   // 264

typedef float f32x2 __attribute__((ext_vector_type(2)));
typedef float f32x4 __attribute__((ext_vector_type(4)));
typedef short s16x8 __attribute__((ext_vector_type(8)));
typedef _Float16 f16x4 __attribute__((ext_vector_type(4)));
typedef unsigned int u32x2 __attribute__((ext_vector_type(2)));

// packed fp32 fma with src0 broadcast from low/high half (VOP3P op_sel)
#define PKFMA_LO(acc, a, b) asm("v_pk_fma_f32 %0, %1, %2, %0 op_sel:[0,0,0] op_sel_hi:[0,1,1]" : "+v"(acc) : "v"(a), "v"(b))
#define PKFMA_HI(acc, a, b) asm("v_pk_fma_f32 %0, %1, %2, %0 op_sel:[1,0,0] op_sel_hi:[1,1,1]" : "+v"(acc) : "v"(a), "v"(b))
#define PKFMA_LO_INIT(dst, a, b, c) asm("v_pk_fma_f32 %0, %1, %2, %3 op_sel:[0,0,0] op_sel_hi:[0,1,1]" : "=v"(dst) : "v"(a), "v"(b), "v"(c))
// D.f32 = f16(src0 half) * 1.0 + src2.f32   (exact fp16->fp32 convert-and-add)
#define FMAMIX_LO(dst, h2, add) asm("v_fma_mix_f32 %0, %1, 1.0, %2 op_sel:[0,0,0] op_sel_hi:[1,0,0]" : "=v"(dst) : "v"(h2), "v"(add))
#define FMAMIX_HI(dst, h2, add) asm("v_fma_mix_f32 %0, %1, 1.0, %2 op_sel:[1,0,0] op_sel_hi:[1,0,0]" : "=v"(dst) : "v"(h2), "v"(add))

#define L2E 1.44269504088896340736f
#define LN2 0.69314718055994530942f
#define OPITCH 520   // fp16 pitch for LDS out-tile: 1040B rows (16B-aligned)

__device__ __forceinline__ unsigned short f2bf(float x){
    unsigned u = __float_as_uint(x);
    return (unsigned short)((u + 0x7FFFu + ((u>>16)&1u)) >> 16);
}

// h = relu(x @ W_emb + b_emb)   [N,16]@[16,128]
__global__ void embed_kernel(const float* __restrict__ x, const float* __restrict__ We,
                             const float* __restrict__ be, float* __restrict__ h, int N){
    int idx = blockIdx.x*blockDim.x + threadIdx.x;
    if (idx >= N*H) return;
    int n = idx >> 7, f = idx & 127;
    float a = be[f];
    #pragma unroll
    for (int k=0;k<16;k++) a = fmaf(x[n*16+k], We[k*H+f], a);
    h[idx] = fmaxf(a, 0.f);
}

__global__ void hist_kernel(const int* __restrict__ dstI, int* __restrict__ counts, int E){
    int e = blockIdx.x*blockDim.x + threadIdx.x;
    if (e < E) atomicAdd(&counts[dstI[e]], 1);
}

__global__ __launch_bounds__(1024) void scan1(const int* __restrict__ counts, int* __restrict__ incl,
                                              int* __restrict__ bsums, int N){
    __shared__ int lds[1024];
    int t = threadIdx.x;
    int i = blockIdx.x*1024 + t;
    int v = (i < N) ? counts[i] : 0;
    lds[t] = v;
    __syncthreads();
    for (int off=1; off<1024; off<<=1){
        int add = (t>=off) ? lds[t-off] : 0;
        __syncthreads();
        lds[t] += add;
        __syncthreads();
    }
    if (i < N) incl[i] = lds[t];
    if (t == 1023) bsums[blockIdx.x] = lds[1023];
}

// single-wave shfl exclusive scan (nb <= 64 fast path; serial fallback otherwise)
__global__ __launch_bounds__(64) void scan2(int* bsums, int nb){
    int t = threadIdx.x;
    if (nb <= 64){
        int orig = (t < nb) ? bsums[t] : 0;
        int v = orig;
        for (int off=1; off<64; off<<=1){
            int n = __shfl_up(v, off);
            if (t >= off) v += n;
        }
        if (t < nb) bsums[t] = v - orig;
    } else if (t == 0){
        int run = 0;
        for (int b=0;b<nb;b++){ int v = bsums[b]; bsums[b] = run; run += v; }
    }
}

__global__ __launch_bounds__(1024) void scan3(const int* incl, const int* __restrict__ counts,
                                              const int* __restrict__ bsums, int* __restrict__ rowptr,
                                              int* cursor, int N, int E){
    int i = blockIdx.x*1024 + threadIdx.x;
    if (i >= N) return;
    int ex = incl[i] - counts[i] + bsums[blockIdx.x];
    rowptr[i] = ex;
    cursor[i] = ex;
    if (i == N-1) rowptr[N] = E;
}

__global__ void scatter_kernel(const int* __restrict__ srcI, const int* __restrict__ dstI,
                               const float* __restrict__ eattr, int* __restrict__ cursor,
                               int* __restrict__ src_s, float* __restrict__ ea_s, int E){
    int e = blockIdx.x*blockDim.x + threadIdx.x;
    if (e >= E) return;
    int d = dstI[e];
    int pos = atomicAdd(&cursor[d], 1);
    src_s[pos] = srcI[e];
    const float4* s4 = (const float4*)(eattr + (size_t)e*EFD);
    float4* o4 = (float4*)(ea_s + (size_t)pos*EFD);
    o4[0] = s4[0]; o4[1] = s4[1];
}

// Pack node-part weights (rows 0..255 of Wf/Ws, all 4 layers) into per-lane MFMA B
// fragments, split hi/lo bf16. Index: idx = ((layer*4 + w)*4 + ks)*8*64 + ct*64 + lane.
__global__ __launch_bounds__(256) void wpack_kernel(const float* __restrict__ Wf, const float* __restrict__ Ws,
        s16x8* __restrict__ bhi, s16x8* __restrict__ blo){
    int idx = blockIdx.x*256 + threadIdx.x;   // 32768 total
    int l = idx & 63, ct = (idx>>6)&7, ks = (idx>>9)&3, w = (idx>>11)&3, layer = idx>>13;
    int cp = w*128 + ct*16 + (l&15);
    int k0 = ks*32 + ((l>>4)<<3);
    const float* WfL = Wf + (size_t)layer*ZDIM*H;
    const float* WsL = Ws + (size_t)layer*ZDIM*H;
    int colIn = cp & 127;
    int sel = cp >> 7;
    const float* Wm = (sel & 1) ? WsL : WfL;
    int krow = (sel >> 1) ? H : 0;
    s16x8 vh, vl;
    #pragma unroll
    for (int e=0;e<8;e++){
        float v = Wm[(size_t)(krow + k0 + e)*H + colIn];
        unsigned short hb = f2bf(v);
        float rem = v - __uint_as_float(((unsigned)hb)<<16);
        vh[e] = (short)hb;
        vl[e] = (short)f2bf(rem);
    }
    bhi[idx] = vh;
    blo[idx] = vl;
}

// Persistent [N,128]@[128,512] GEMM, bf16 MFMA 3-term hi/lo split (~fp32 accuracy).
// 256 blocks x 512 threads (8 waves), register-resident B fragments, grid-stride tiles.
// Fused BN-apply (layers>0): h += relu(xn*sc+sh) in-place. Output: unified fp16 table
// T16[N][512]: 0..255 dst {Fd2k,Fd2k+1,Sd2k,Sd2k+1} (bias baked), 256..511 src part.
// Epilogue via LDS out-tile (pitch 520 fp16) -> fully-coalesced 16B stores.
// Pre-scaled by log2(e) for exp2-domain gates.
__global__ __launch_bounds__(512, 2) void table_mfma(
        float* __restrict__ h, const float* __restrict__ xn, const float* __restrict__ scsh,
        const s16x8* __restrict__ bhi, const s16x8* __restrict__ blo,
        const float* __restrict__ bf_l, const float* __restrict__ bs_l,
        _Float16* __restrict__ T16, int N, int layer, int ntiles){
    __shared__ __align__(16) short amat[2][32*136];      // hi/lo, 272B row pitch
    __shared__ __align__(16) _Float16 outs[32*OPITCH];   // 32 x 520 fp16 (33KB)
    const int t = threadIdx.x;
    const int lane = t & 63, W = t >> 6;
    const int ow = W >> 1, ctbase = (W & 1)*4;
    const int rbase = lane & 15, kg = lane >> 4;

    s16x8 Bh[4][4], Bl[4][4];
    {
        const size_t bbase = ((size_t)layer*4 + ow)*2048;
        #pragma unroll
        for (int ks=0;ks<4;ks++)
            #pragma unroll
            for (int c=0;c<4;c++){
                Bh[ks][c] = bhi[bbase + ks*512 + (ctbase+c)*64 + lane];
                Bl[ks][c] = blo[bbase + ks*512 + (ctbase+c)*64 + lane];
            }
        #pragma unroll
        for (int ks=0;ks<4;ks++)
            #pragma unroll
            for (int c=0;c<4;c++) asm volatile("" : "+v"(Bh[ks][c]), "+v"(Bl[ks][c]));
    }
    int offT[4];
    float bv[4];
    #pragma unroll
    for (int c=0;c<4;c++){
        const int cl = (ctbase+c)*16 + rbase;
        offT[c] = (ow>>1)*256 + ((cl>>1)<<2) + ((ow&1)<<1) + (cl&1);
        bv[c] = (ow == 0) ? bf_l[cl]*L2E : (ow == 1) ? bs_l[cl]*L2E : 0.f;
    }
    const int srow = t >> 4;          // 0..31
    const int kb = (t & 15)*8;        // 0..120
    float sc8[8], sh8[8];
    if (scsh){
        #pragma unroll
        for (int q=0;q<8;q+=4){
            *(float4*)&sc8[q] = *(const float4*)(scsh + kb + q);
            *(float4*)&sh8[q] = *(const float4*)(scsh + H + kb + q);
        }
    }

    for (int tile = blockIdx.x; tile < ntiles; tile += gridDim.x){
        const int n0 = tile*32;
        {   // ---- stage 32x128 tile (fused BN for layers>0) ----
            const int gn = n0 + srow;
            const bool valid = gn < N;
            float* hr = h + (size_t)gn*H + kb;
            float vv[8];
            if (scsh){
                const float* xr = xn + (size_t)gn*H + kb;
                #pragma unroll
                for (int q=0;q<8;q+=4){
                    float4 xv = valid ? *(const float4*)(xr + q) : make_float4(0.f,0.f,0.f,0.f);
                    float4 hv = valid ? *(const float4*)(hr + q) : make_float4(0.f,0.f,0.f,0.f);
                    vv[q]   = hv.x + fmaxf(fmaf(xv.x, sc8[q],   sh8[q]),   0.f);
                    vv[q+1] = hv.y + fmaxf(fmaf(xv.y, sc8[q+1], sh8[q+1]), 0.f);
                    vv[q+2] = hv.z + fmaxf(fmaf(xv.z, sc8[q+2], sh8[q+2]), 0.f);
                    vv[q+3] = hv.w + fmaxf(fmaf(xv.w, sc8[q+3], sh8[q+3]), 0.f);
                }
                if (valid){
                    #pragma unroll
                    for (int q=0;q<8;q+=4){
                        float4 o; o.x=vv[q]; o.y=vv[q+1]; o.z=vv[q+2]; o.w=vv[q+3];
                        *(float4*)(hr + q) = o;
                    }
                }
            } else {
                #pragma unroll
                for (int q=0;q<8;q+=4){
                    float4 hv = valid ? *(const float4*)(hr + q) : make_float4(0.f,0.f,0.f,0.f);
                    vv[q]=hv.x; vv[q+1]=hv.y; vv[q+2]=hv.z; vv[q+3]=hv.w;
                }
            }
            s16x8 hv2, lv2;
            #pragma unroll
            for (int q=0;q<8;q++){
                unsigned short hb = f2bf(vv[q]);
                float rem = vv[q] - __uint_as_float(((unsigned)hb)<<16);
                hv2[q] = (short)hb;
                lv2[q] = (short)f2bf(rem);
            }
            *(s16x8*)&amat[0][srow*136 + kb] = hv2;
            *(s16x8*)&amat[1][srow*136 + kb] = lv2;
        }
        __syncthreads();
        // ---- MFMA ----
        f32x4 acc[2][4];
        #pragma unroll
        for (int rt=0;rt<2;rt++)
            #pragma unroll
            for (int c=0;c<4;c++){ acc[rt][c][0]=0.f; acc[rt][c][1]=0.f; acc[rt][c][2]=0.f; acc[rt][c][3]=0.f; }
        #pragma unroll
        for (int ks=0;ks<4;ks++){
            s16x8 ah[2], al[2];
            #pragma unroll
            for (int rt=0;rt<2;rt++){
                const int ao = (rbase + 16*rt)*136 + ks*32 + kg*8;
                ah[rt] = *(const s16x8*)&amat[0][ao];
                al[rt] = *(const s16x8*)&amat[1][ao];
            }
            #pragma unroll
            for (int c=0;c<4;c++)
                #pragma unroll
                for (int rt=0;rt<2;rt++){
                    acc[rt][c] = __builtin_amdgcn_mfma_f32_16x16x32_bf16(ah[rt], Bh[ks][c], acc[rt][c], 0, 0, 0);
                    acc[rt][c] = __builtin_amdgcn_mfma_f32_16x16x32_bf16(ah[rt], Bl[ks][c], acc[rt][c], 0, 0, 0);
                    acc[rt][c] = __builtin_amdgcn_mfma_f32_16x16x32_bf16(al[rt], Bh[ks][c], acc[rt][c], 0, 0, 0);
                }
        }
        // ---- C fragments -> LDS out-tile (fp16) ----
        #pragma unroll
        for (int c=0;c<4;c++)
            #pragma unroll
            for (int rt=0;rt<2;rt++){
                const int nrow = 16*rt + kg*4;
                #pragma unroll
                for (int r=0;r<4;r++)
                    outs[(nrow + r)*OPITCH + offT[c]] = (_Float16)fmaf(acc[rt][c][r], L2E, bv[c]);
            }
        __syncthreads();
        // ---- coalesced copy-out: wave W handles rows W, W+8, W+16, W+24; 1KB/row ----
        {
            const int colb = (t & 63)*8;   // fp16 offset, 16B per lane
            #pragma unroll
            for (int ps=0; ps<4; ps++){
                const int row = ps*8 + W;
                const int nd = n0 + row;
                if (nd < N){
                    uint4 v = *(const uint4*)&outs[row*OPITCH + colb];
                    *(uint4*)(T16 + (size_t)nd*512 + colb) = v;
                }
            }
        }
        __syncthreads();
    }
}

// One wave per node; weights in LDS->regs; packed fp32 fma; exp2-domain gates.
// R12's unroll-by-2 pipeline (JID clamp, scalar epilogue) verbatim; only the table
// reads changed: dst gates from T16 dst half (bias baked), src GATHER from T16+256.
__global__ __launch_bounds__(256, 4) void agg_kernel(
        const _Float16* __restrict__ T16,
        const int* __restrict__ rowptr, const int* __restrict__ src_s, const float* __restrict__ ea_s,
        const float* __restrict__ Wf_l, const float* __restrict__ Ws_l,
        const float* __restrict__ h, float* __restrict__ xn, int N){
    __shared__ float wE[2048];   // [8][128] Wf edge rows, then [8][128] Ws edge rows (scaled by log2e)
    const int t = threadIdx.x;
    {
        const float4* a = (const float4*)(Wf_l + 2*H*H);
        const float4* b = (const float4*)(Ws_l + 2*H*H);
        float4 va = a[t], vb = b[t];
        va.x*=L2E; va.y*=L2E; va.z*=L2E; va.w*=L2E;
        vb.x*=L2E; vb.y*=L2E; vb.z*=L2E; vb.w*=L2E;
        ((float4*)wE)[t] = va;
        ((float4*)wE)[256 + t] = vb;
    }
    __syncthreads();
    const int k = t & 63;
    const int i = blockIdx.x*4 + (t >> 6);
    if (i >= N) return;
    f32x2 wef2[8], wes2[8];
    #pragma unroll
    for (int r=0;r<8;r++){
        wef2[r] = *(const f32x2*)&wE[r*128 + 2*k];
        wes2[r] = *(const f32x2*)&wE[1024 + r*128 + 2*k];
    }
    #pragma unroll
    for (int r=0;r<8;r++) asm volatile("" : "+v"(wef2[r]), "+v"(wes2[r]));
    // dst gate bases from T16 dst half (bias baked, pre-scaled)
    f16x4 dv = *(const f16x4*)(T16 + ((size_t)i << 9) + 4*k);
    f32x2 fd2, sd2;
    fd2.x = (float)dv[0]; fd2.y = (float)dv[1];
    sd2.x = (float)dv[2]; sd2.y = (float)dv[3];
    f32x2 acc = {0.f, 0.f};
    const int e0 = __builtin_amdgcn_readfirstlane(rowptr[i]);
    const int e1 = __builtin_amdgcn_readfirstlane(rowptr[i+1]);
    const int myoff = 4*k;
    const int last = e1 - 1;

    auto JID = [&](int e)->int {
        int ec = (e <= last) ? e : last;
        return __builtin_amdgcn_readfirstlane(src_s[ec]);
    };
    auto GATHER = [&](int j)->f16x4 {
        return *(const f16x4*)(T16 + 256 + (((size_t)(unsigned)j) << 9) + myoff);
    };
    auto BODY = [&](int e, f16x4 tv){
        const float* ep = ea_s + (size_t)e*EFD;
        f32x4 eaA = *(const f32x4*)(ep);
        f32x4 eaB = *(const f32x4*)(ep + 4);
        f32x2 ea0 = __builtin_shufflevector(eaA, eaA, 0, 1);
        f32x2 ea1 = __builtin_shufflevector(eaA, eaA, 2, 3);
        f32x2 ea2 = __builtin_shufflevector(eaB, eaB, 0, 1);
        f32x2 ea3 = __builtin_shufflevector(eaB, eaB, 2, 3);
        f32x2 ef, es;
        PKFMA_LO_INIT(ef, ea0, wef2[0], fd2);
        PKFMA_HI(ef, ea0, wef2[1]);
        PKFMA_LO(ef, ea1, wef2[2]); PKFMA_HI(ef, ea1, wef2[3]);
        PKFMA_LO(ef, ea2, wef2[4]); PKFMA_HI(ef, ea2, wef2[5]);
        PKFMA_LO(ef, ea3, wef2[6]); PKFMA_HI(ef, ea3, wef2[7]);
        PKFMA_LO_INIT(es, ea0, wes2[0], sd2);
        PKFMA_HI(es, ea0, wes2[1]);
        PKFMA_LO(es, ea1, wes2[2]); PKFMA_HI(es, ea1, wes2[3]);
        PKFMA_LO(es, ea2, wes2[4]); PKFMA_HI(es, ea2, wes2[5]);
        PKFMA_LO(es, ea3, wes2[6]); PKFMA_HI(es, ea3, wes2[7]);
        u32x2 tu = *(u32x2*)&tv;
        float gx, gy, px, py;
        FMAMIX_LO(gx, tu.x, ef.x);
        FMAMIX_HI(gy, tu.x, ef.y);
        FMAMIX_LO(px, tu.y, es.x);
        FMAMIX_HI(py, tu.y, es.y);
        float sx = __builtin_amdgcn_rcpf(1.0f + __builtin_amdgcn_exp2f(-gx));
        float sy = __builtin_amdgcn_rcpf(1.0f + __builtin_amdgcn_exp2f(-gy));
        float tx = fmaxf(px, 0.f) + __builtin_amdgcn_logf(1.0f + __builtin_amdgcn_exp2f(-fabsf(px)));
        float ty = fmaxf(py, 0.f) + __builtin_amdgcn_logf(1.0f + __builtin_amdgcn_exp2f(-fabsf(py)));
        acc.x = fmaf(sx*tx, LN2, acc.x);
        acc.y = fmaf(sy*ty, LN2, acc.y);
    };

    if (e0 < e1){
        int j0 = JID(e0);
        int j1 = JID(e0+1);
        f16x4 tvA = GATHER(j0);
        f16x4 tvB = GATHER(j1);
        int jA = JID(e0+2);     // id for edge e+2 (gathered into tvA after BODY(e))
        int jB = JID(e0+3);     // id for edge e+3
        int e = e0;
        for (; e + 1 < e1; e += 2){
            int jA2 = JID(e+4);
            BODY(e, tvA);
            tvA = GATHER(jA);   // data for e+2, consumed next iteration
            int jB2 = JID(e+5);
            BODY(e+1, tvB);
            tvB = GATHER(jB);   // data for e+3
            jA = jA2; jB = jB2;
        }
        if (e < e1) BODY(e, tvA);
    }
    f32x2 hv = *(const f32x2*)(h + ((size_t)i << 7) + 2*k);
    f32x2 o = acc + hv;
    *(f32x2*)(xn + ((size_t)i << 7) + 2*k) = o;
}

__global__ __launch_bounds__(256) void stats_kernel(const float* __restrict__ xn, double* __restrict__ sums, int N){
    __shared__ double l1[128], l2[128];
    const int f = threadIdx.x & 127;
    const int half = threadIdx.x >> 7;
    const int nb = gridDim.x;
    const int per = (N + nb - 1)/nb;
    const int r0 = blockIdx.x*per;
    const int r1 = min(N, r0+per);
    double s = 0.0, s2 = 0.0;
    for (int r=r0+half; r<r1; r+=2){
        float v = xn[(size_t)r*H + f];
        s += v; s2 += (double)v*(double)v;
    }
    if (half == 1){ l1[f] = s; l2[f] = s2; }
    __syncthreads();
    if (half == 0){
        s += l1[f]; s2 += l2[f];
        atomicAdd(&sums[f], s);
        atomicAdd(&sums[H+f], s2);
    }
}

__global__ void finalize_bn(double* __restrict__ sums, const float* __restrict__ gamma_l,
                            const float* __restrict__ beta_l, float* __restrict__ scsh, int N){
    int f = threadIdx.x;
    if (f >= H) return;
    double mu = sums[f]/(double)N;
    double var = sums[H+f]/(double)N - mu*mu;
    if (var < 0.0) var = 0.0;
    float sc = (float)((double)gamma_l[f] / sqrt(var + 1e-5));
    scsh[f]   = sc;
    scsh[H+f] = (float)((double)beta_l[f] - mu*(double)sc);
    sums[f] = 0.0;       // reset for next layer
    sums[H+f] = 0.0;
}

// One block per graph: binary-search sorted batch for the segment; final-layer BN applied
// on the fly: pooled mean of h[r] + relu(xn[r]*sc+sh); then the 3-layer MLP.
__global__ __launch_bounds__(128) void pool_mlp_kernel(const float* __restrict__ h, const float* __restrict__ xn,
        const float* __restrict__ scsh, const int* __restrict__ batch,
        const float* __restrict__ W1, const float* __restrict__ b1,
        const float* __restrict__ W2, const float* __restrict__ b2,
        const float* __restrict__ Wo, const float* __restrict__ bo,
        float* __restrict__ out, int N){
    __shared__ float row[128];
    __shared__ float g1[64];
    __shared__ float g2[32];
    const int g = blockIdx.x;
    const int t = threadIdx.x;
    int lo = 0, hi = N;
    while (lo < hi){ int m = (lo+hi)>>1; if (batch[m] < g) lo = m+1; else hi = m; }
    const int s0 = lo;
    hi = N;
    while (lo < hi){ int m = (lo+hi)>>1; if (batch[m] < g+1) lo = m+1; else hi = m; }
    const int s1 = lo;
    const float sc = scsh[t], sh = scsh[H+t];
    float acc = 0.f;
    for (int r = s0; r < s1; ++r){
        float hv = h[(size_t)r*H + t];
        float xv = xn[(size_t)r*H + t];
        acc += hv + fmaxf(fmaf(xv, sc, sh), 0.f);
    }
    const float inv = 1.0f/fmaxf((float)(s1-s0), 1.0f);
    row[t] = acc*inv;
    __syncthreads();
    if (t < 64){
        float a = b1[t];
        #pragma unroll 4
        for (int i2=0;i2<128;i2++) a = fmaf(row[i2], W1[i2*64+t], a);
        g1[t] = fmaxf(a, 0.f);
    }
    __syncthreads();
    if (t < 32){
        float b = b2[t];
        #pragma unroll 4
        for (int i2=0;i2<64;i2++) b = fmaf(g1[i2], W2[i2*32+t], b);
        g2[t] = fmaxf(b, 0.f);
    }
    __syncthreads();
    if (t < 64){
        float p = (t < 32) ? g2[t]*Wo[t] : 0.f;
        for (int off=32; off>0; off>>=1) p += __shfl_down(p, off);
        if (t == 0) out[g] = p + bo[0];
    }
}

extern "C" void kernel_launch(void* const* d_in, const int* in_sizes, int n_in,
                              void* d_out, int out_size, void* d_ws, size_t ws_size,
                              hipStream_t stream){
    const float* x     = (const float*)d_in[0];
    const int*   eidx  = (const int*)d_in[1];
    const float* eattr = (const float*)d_in[2];
    const int*   batch = (const int*)d_in[3];
    const float* W_emb = (const float*)d_in[4];
    const float* b_emb = (const float*)d_in[5];
    const float* Wf    = (const float*)d_in[6];
    const float* bf    = (const float*)d_in[7];
    const float* Wsm   = (const float*)d_in[8];
    const float* bs    = (const float*)d_in[9];
    const float* gamma = (const float*)d_in[10];
    const float* beta  = (const float*)d_in[11];
    const float* W1    = (const float*)d_in[12];
    const float* b1    = (const float*)d_in[13];
    const float* W2    = (const float*)d_in[14];
    const float* b2    = (const float*)d_in[15];
    const float* Wo    = (const float*)d_in[16];
    const float* bo    = (const float*)d_in[17];
    float* out = (float*)d_out;

    const int N = in_sizes[0]/16;
    const int E = in_sizes[1]/2;
    const int G = out_size;

    const int* srcI = eidx;
    const int* dstI = eidx + E;

    char* p = (char*)d_ws;
    auto alloc = [&](size_t bytes)->char*{ char* r = p; p += (bytes + 255) & ~255ull; return r; };
    float*     h      = (float*)     alloc((size_t)N*H*4);
    float*     xn     = (float*)     alloc((size_t)N*H*4);
    _Float16*  T16    = (_Float16*)  alloc((size_t)N*512*2);
    float*     ea_s   = (float*)     alloc((size_t)E*EFD*4);
    int*       src_s  = (int*)       alloc((size_t)E*4);
    int*       rowptr = (int*)       alloc((size_t)(N+1)*4);
    int*       cursor = (int*)       alloc((size_t)N*4);   // also incl-scan temp
    int*       counts = (int*)       alloc((size_t)N*4);
    int*       bsums  = (int*)       alloc(256*4);
    double*    sums   = (double*)    alloc(2*H*8);
    float*     scsh   = (float*)     alloc(2*H*4);
    s16x8*     bhi    = (s16x8*)     alloc((size_t)NLAYER*8192*16);
    s16x8*     blo    = (s16x8*)     alloc((size_t)NLAYER*8192*16);

    const int thr = 256;
    hipMemsetAsync(counts, 0, (size_t)N*4, stream);
    hipMemsetAsync(sums, 0, 2*H*8, stream);
    embed_kernel<<<(N*H + thr-1)/thr, thr, 0, stream>>>(x, W_emb, b_emb, h, N);
    hist_kernel<<<(E + thr-1)/thr, thr, 0, stream>>>(dstI, counts, E);
    int nb = (N + 1023)/1024;
    scan1<<<nb, 1024, 0, stream>>>(counts, cursor, bsums, N);
    scan2<<<1, 64, 0, stream>>>(bsums, nb);
    scan3<<<nb, 1024, 0, stream>>>(cursor, counts, bsums, rowptr, cursor, N, E);
    scatter_kernel<<<(E + thr-1)/thr, thr, 0, stream>>>(srcI, dstI, eattr, cursor, src_s, ea_s, E);
    wpack_kernel<<<128, 256, 0, stream>>>(Wf, Wsm, bhi, blo);

    const int ntiles = (N + 31)/32;
    for (int l=0;l<NLAYER;l++){
        table_mfma<<<256, 512, 0, stream>>>(h, xn, (l==0)?nullptr:scsh, bhi, blo,
                                            bf + l*H, bs + l*H, T16, N, l, ntiles);
        agg_kernel<<<(N+3)/4, 256, 0, stream>>>(T16, rowptr, src_s, ea_s,
                                                Wf + (size_t)l*ZDIM*H, Wsm + (size_t)l*ZDIM*H, h, xn, N);
        stats_kernel<<<256, 256, 0, stream>>>(xn, sums, N);
        finalize_bn<<<1, 128, 0, stream>>>(sums, gamma + l*H, beta + l*H, scsh, N);
    }

    pool_mlp_kernel<<<G, 128, 0, stream>>>(h, xn, scsh, batch, W1, b1, W2, b2, Wo, bo, out, N);
}